// Round 7
// baseline (2026.557 us; speedup 1.0000x reference)
//
#include <hip/hip_runtime.h>
#include <hip/hip_bf16.h>

#define NN 100000
#define EE 1600000
#define DD 128
#define EPSc 0.1f
#define NSH 16          // src shards (6250 nodes = 0.8 MB fp8 rows each)
#define SHDIV 6250
#define NBUK 256        // dst-range buckets for CSR build
#define BDIV 391        // nodes per bucket (391*256 >= NN)
#define BCAP 7200       // max edges per bucket (avg 6250, ~11 sigma pad)

typedef unsigned short bfu;
typedef __attribute__((ext_vector_type(8))) short short8;   // 8 bf16 = 4 VGPRs
typedef __attribute__((ext_vector_type(4))) float f32x4;
typedef __attribute__((ext_vector_type(2))) float f32x2;

__device__ __forceinline__ float bf2f(bfu s) {
    union { unsigned u; float f; } c; c.u = ((unsigned)s) << 16; return c.f;
}
__device__ __forceinline__ bfu f2bf(float f) {
    union { float f; unsigned u; } c; c.f = f;
    unsigned u = c.u + 0x7fffu + ((c.u >> 16) & 1u);   // RNE
    return (bfu)(u >> 16);
}
__device__ __forceinline__ unsigned pk8(float a, float b, float c, float d) {
    int r = 0;
    r = __builtin_amdgcn_cvt_pk_fp8_f32(a, b, r, false);
    r = __builtin_amdgcn_cvt_pk_fp8_f32(c, d, r, true);
    return (unsigned)r;
}
__device__ __forceinline__ unsigned char enc8(float a) {
    return (unsigned char)(__builtin_amdgcn_cvt_pk_fp8_f32(a, a, 0, false) & 0xFF);
}
__device__ __forceinline__ short8 e8bf(uint2 u) {
    f32x2 p0 = __builtin_amdgcn_cvt_pk_f32_fp8((int)u.x, false);
    f32x2 p1 = __builtin_amdgcn_cvt_pk_f32_fp8((int)u.x, true);
    f32x2 p2 = __builtin_amdgcn_cvt_pk_f32_fp8((int)u.y, false);
    f32x2 p3 = __builtin_amdgcn_cvt_pk_f32_fp8((int)u.y, true);
    short8 s;
    s[0] = (short)f2bf(p0[0]); s[1] = (short)f2bf(p0[1]);
    s[2] = (short)f2bf(p1[0]); s[3] = (short)f2bf(p1[1]);
    s[4] = (short)f2bf(p2[0]); s[5] = (short)f2bf(p2[1]);
    s[6] = (short)f2bf(p3[0]); s[7] = (short)f2bf(p3[1]);
    return s;
}

// ---------------- CSR build (per-(dst,src-shard) counting sort, bucketed) ----------------

// K1: histogram over (dst, src-shard)
__global__ __launch_bounds__(256) void hist_kernel(const int* __restrict__ src,
                                                   const int* __restrict__ dst,
                                                   int* __restrict__ cnt, int e_cnt) {
    int e = blockIdx.x * 256 + threadIdx.x;
    if (e < e_cnt) {
        int d = dst[e];
        int sh = (unsigned)src[e] / SHDIV;
        atomicAdd(&cnt[d * NSH + sh], 1);
    }
}

// K2: per-node degree, dinv, in-place exclusive prefix over the 16 shard counts
__global__ __launch_bounds__(256) void offsets_kernel(int* __restrict__ cnt,
                                                      int* __restrict__ ideg,
                                                      float* __restrict__ dinv, int n) {
    int i = blockIdx.x * 256 + threadIdx.x;
    if (i >= n) return;
    int c[NSH];
    #pragma unroll
    for (int s = 0; s < NSH; ++s) c[s] = cnt[i * NSH + s];
    int run = 0;
    #pragma unroll
    for (int s = 0; s < NSH; ++s) { int v = c[s]; cnt[i * NSH + s] = run; run += v; }
    ideg[i] = run;
    dinv[i] = (run > 0) ? rsqrtf((float)run) : 0.0f;
}

__global__ __launch_bounds__(256) void partial_sum_kernel(const int* __restrict__ ideg,
                                                          int* __restrict__ partials, int n) {
    __shared__ int sm[256];
    int i = blockIdx.x * 256 + threadIdx.x;
    sm[threadIdx.x] = (i < n) ? ideg[i] : 0;
    __syncthreads();
    for (int off = 128; off > 0; off >>= 1) {
        if ((int)threadIdx.x < off) sm[threadIdx.x] += sm[threadIdx.x + off];
        __syncthreads();
    }
    if (threadIdx.x == 0) partials[blockIdx.x] = sm[0];
}

__global__ __launch_bounds__(512) void scan_partials_kernel(int* __restrict__ partials,
                                                            int* __restrict__ row_ptr,
                                                            int nb, int n) {
    __shared__ int sm[512];
    int v = ((int)threadIdx.x < nb) ? partials[threadIdx.x] : 0;
    sm[threadIdx.x] = v;
    __syncthreads();
    for (int off = 1; off < 512; off <<= 1) {
        int t = (threadIdx.x >= (unsigned)off) ? sm[threadIdx.x - off] : 0;
        __syncthreads();
        sm[threadIdx.x] += t;
        __syncthreads();
    }
    if ((int)threadIdx.x < nb) partials[threadIdx.x] = sm[threadIdx.x] - v;
    if (threadIdx.x == 511) row_ptr[n] = sm[511];
}

// K3: node base scan + absolute per-(node,shard) cursors
__global__ __launch_bounds__(256) void scan_block_kernel(const int* __restrict__ ideg,
                                                         const int* __restrict__ partials,
                                                         const int* __restrict__ prefix16,
                                                         int* __restrict__ row_ptr,
                                                         int* __restrict__ cur16, int n) {
    __shared__ int sm[256];
    int i = blockIdx.x * 256 + threadIdx.x;
    int v = (i < n) ? ideg[i] : 0;
    sm[threadIdx.x] = v;
    __syncthreads();
    for (int off = 1; off < 256; off <<= 1) {
        int t = (threadIdx.x >= (unsigned)off) ? sm[threadIdx.x - off] : 0;
        __syncthreads();
        sm[threadIdx.x] += t;
        __syncthreads();
    }
    if (i < n) {
        int excl = partials[blockIdx.x] + sm[threadIdx.x] - v;
        row_ptr[i] = excl;
        #pragma unroll
        for (int s = 0; s < NSH; ++s) cur16[i * NSH + s] = excl + prefix16[i * NSH + s];
    }
}

// K4: scatter edges into dst-range buckets (sequential per-bucket writes -> coalesced)
__global__ __launch_bounds__(256) void bucket_scatter_kernel(const int* __restrict__ src,
                                                             const int* __restrict__ dst,
                                                             const float* __restrict__ dinv,
                                                             int* __restrict__ bcur,
                                                             uint2* __restrict__ buckets,
                                                             int e_cnt) {
    int e = blockIdx.x * 256 + threadIdx.x;
    if (e < e_cnt) {
        int d = dst[e], s = src[e];
        unsigned b = (unsigned)d / BDIV;
        int pos = atomicAdd(&bcur[b], 1);
        if (pos < BCAP) {
            unsigned vb = __float_as_uint(dinv[s] * dinv[d]);
            unsigned r = vb + 0xFFFFu + ((vb >> 17) & 1u);   // RNE to 15-bit float
            buckets[(size_t)b * BCAP + pos] = make_uint2((r & 0xFFFE0000u) | (unsigned)s,
                                                         (unsigned)d);
        }
    }
}

// K5: place bucket edges at final (dst, src-shard)-sorted positions (L2-resident window)
__global__ __launch_bounds__(256) void bucket_place_kernel(const uint2* __restrict__ buckets,
                                                           const int* __restrict__ bcur,
                                                           int* __restrict__ cur16,
                                                           unsigned* __restrict__ cvp) {
    int b = blockIdx.x;
    int cnt = bcur[b]; if (cnt > BCAP) cnt = BCAP;
    for (int i = threadIdx.x; i < cnt; i += 256) {
        uint2 w = buckets[(size_t)b * BCAP + i];
        unsigned col = w.x & 0x1FFFFu;
        int sh = col / SHDIV;
        int pos = atomicAdd(&cur16[w.y * NSH + sh], 1);
        cvp[pos] = w.x;
    }
}

// ------------- weight -> bf16 MFMA-fragment-order transform -------------

__global__ __launch_bounds__(256) void wfrag_kernel(const float* __restrict__ conv_ws,
                                                    const float* __restrict__ ro_w,
                                                    bfu* __restrict__ Wf) {
    int m = blockIdx.x;   // 0..3
    const float* W = (m < 3) ? conv_ws + m * 16384 : ro_w;
    bfu* T = Wf + m * 16384;
    for (int j = 0; j < 64; ++j) {
        int i = threadIdx.x + j * 256;       // i = k*128 + n
        int k = i >> 7, n = i & 127;
        int nt = n >> 4, ks = k >> 5, kg = (k >> 3) & 3, jj = k & 7;
        int l = kg * 16 + (n & 15);
        int flat = ((nt * 4 + ks) * 64 + l) * 8 + jj;
        T[flat] = f2bf(W[i]);
    }
}

// ---------------- propagation (fp8 in / fp8 out, f32 accum) ----------------
// Edge list is (dst, src-shard)-sorted: concurrent waves walk shards roughly in
// phase, keeping the instantaneous gather working set L2-resident.

__device__ __forceinline__ void acc8f8(uint2 u, float v, float* acc) {
    f32x2 p0 = __builtin_amdgcn_cvt_pk_f32_fp8((int)u.x, false);
    f32x2 p1 = __builtin_amdgcn_cvt_pk_f32_fp8((int)u.x, true);
    f32x2 p2 = __builtin_amdgcn_cvt_pk_f32_fp8((int)u.y, false);
    f32x2 p3 = __builtin_amdgcn_cvt_pk_f32_fp8((int)u.y, true);
    acc[0] = fmaf(v, p0[0], acc[0]); acc[1] = fmaf(v, p0[1], acc[1]);
    acc[2] = fmaf(v, p1[0], acc[2]); acc[3] = fmaf(v, p1[1], acc[3]);
    acc[4] = fmaf(v, p2[0], acc[4]); acc[5] = fmaf(v, p2[1], acc[5]);
    acc[6] = fmaf(v, p3[0], acc[6]); acc[7] = fmaf(v, p3[1], acc[7]);
}

__global__ __launch_bounds__(256) void prop_kernel(const unsigned char* __restrict__ xin8,
                                                   unsigned char* __restrict__ out8,
                                                   const int* __restrict__ row_ptr,
                                                   const unsigned* __restrict__ cvp, int n) {
    int wid = (blockIdx.x * 256 + threadIdx.x) >> 6;  // one wave per node
    int lane = threadIdx.x & 63;
    if (wid >= n) return;
    int s = row_ptr[wid];
    int deg = row_ptr[wid + 1] - s;
    int g = lane >> 4;        // edge slot group 0..3
    int li = lane & 15;       // 16 lanes cover 128 dims (8 fp8 bytes each)
    float acc[8] = {0.f, 0.f, 0.f, 0.f, 0.f, 0.f, 0.f, 0.f};
    for (int base = 0; base < deg; base += 64) {
        int cnt = deg - base; if (cnt > 64) cnt = 64;
        unsigned el = (lane < cnt) ? cvp[s + base + lane] : 0u;   // coalesced
        for (int q = 0; q < cnt; q += 16) {
            uint2 x[4]; float v[4];
            #pragma unroll
            for (int j = 0; j < 4; ++j) {
                int idx = q + j * 4 + g;
                unsigned c = __shfl(el, idx);
                bool valid = idx < cnt;
                v[j] = valid ? __uint_as_float(c & 0xFFFE0000u) : 0.f;
                x[j] = valid ? *(const uint2*)(xin8 + (size_t)(c & 0x1FFFFu) * DD + li * 8)
                             : make_uint2(0u, 0u);
            }
            #pragma unroll
            for (int j = 0; j < 4; ++j) acc8f8(x[j], v[j], acc);
        }
    }
    #pragma unroll
    for (int k = 0; k < 8; ++k) {
        acc[k] += __shfl_xor(acc[k], 16);
        acc[k] += __shfl_xor(acc[k], 32);
    }
    if (g == 0) {
        uint2 q;
        q.x = pk8(acc[0], acc[1], acc[2], acc[3]);
        q.y = pk8(acc[4], acc[5], acc[6], acc[7]);
        *(uint2*)(out8 + (size_t)wid * DD + li * 8) = q;
    }
}

// ---------------- MFMA matmul: acc = sum_m A_m @ W_m, fused epilogue ----------------

template <int NMAT, bool TANH, bool A8>
__global__ __launch_bounds__(256) void mfma_mm_kernel(const void* __restrict__ A0,
                                                      const void* __restrict__ A1,
                                                      const void* __restrict__ A2,
                                                      const bfu* __restrict__ Wf,
                                                      const float* __restrict__ bias,
                                                      const bfu* __restrict__ base16,
                                                      float* __restrict__ outf,
                                                      bfu* __restrict__ out16,
                                                      unsigned char* __restrict__ out8,
                                                      float scale) {
    int tid = threadIdx.x;
    int wave = tid >> 6, lane = tid & 63;
    int r0 = blockIdx.x * 64 + wave * 16;
    int li = lane & 15, kg = lane >> 4;
    int rowA = r0 + li;
    bool rv = rowA < NN;
    size_t arow = (size_t)(rv ? rowA : 0) * DD;   // elements

    const void* As[3] = {A0, A1, A2};
    short8 a[NMAT][4];
    #pragma unroll
    for (int m = 0; m < NMAT; ++m) {
        #pragma unroll
        for (int ks = 0; ks < 4; ++ks) {
            short8 t;
            if (A8) {
                uint2 u = *(const uint2*)((const unsigned char*)As[m] + arow + ks * 32 + kg * 8);
                t = e8bf(u);
            } else {
                t = *(const short8*)((const bfu*)As[m] + arow + ks * 32 + kg * 8);
            }
            if (!rv) t = (short8)0;
            a[m][ks] = t;
        }
    }

    const short8* Bp = (const short8*)Wf;   // [NMAT][32][64] short8
    f32x4 acc[8];
    #pragma unroll
    for (int nt = 0; nt < 8; ++nt) acc[nt] = (f32x4)(0.f);
    #pragma unroll
    for (int nt = 0; nt < 8; ++nt) {
        #pragma unroll
        for (int m = 0; m < NMAT; ++m) {
            #pragma unroll
            for (int ks = 0; ks < 4; ++ks) {
                short8 b = Bp[m * 2048 + (nt * 4 + ks) * 64 + lane];
                acc[nt] = __builtin_amdgcn_mfma_f32_16x16x32_bf16(a[m][ks], b, acc[nt], 0, 0, 0);
            }
        }
    }

    #pragma unroll
    for (int nt = 0; nt < 8; ++nt) {
        int cc = nt * 16 + li;
        float bv = bias[cc];
        #pragma unroll
        for (int rg = 0; rg < 4; ++rg) {
            int rr = r0 + kg * 4 + rg;
            if (rr < NN) {
                size_t off = (size_t)rr * DD + cc;
                float o = acc[nt][rg];
                if (TANH) {
                    float ov = bf2f(base16[off]) + scale * tanhf(o + bv);
                    if (outf) outf[off] = ov;
                    if (out16) out16[off] = f2bf(ov);
                    out8[off] = enc8(ov);
                } else {
                    outf[off] = o + bv;
                }
            }
        }
    }
}

// ---------------- f32 matmul for embedding: h = x@W + b -> bf16 + fp8 ----------------

__global__ __launch_bounds__(256) void matmul_f32_kernel(const float* __restrict__ A,
                                                         const float* __restrict__ W,
                                                         const float* __restrict__ bias,
                                                         bfu* __restrict__ out16,
                                                         unsigned char* __restrict__ out8) {
    __shared__ float Wl[128][128];
    __shared__ float Al[32][128];
    int tid = threadIdx.x;

    const float4* Wv = (const float4*)W;
    float4* Wlv = (float4*)&Wl[0][0];
    #pragma unroll
    for (int i = 0; i < 16; ++i) Wlv[tid + i * 256] = Wv[tid + i * 256];

    size_t row0 = (size_t)blockIdx.x * 32;
    const float4* Av = (const float4*)(A + row0 * DD);
    float4* Alv = (float4*)&Al[0][0];
    #pragma unroll
    for (int i = 0; i < 4; ++i) Alv[tid + i * 256] = Av[tid + i * 256];
    __syncthreads();

    int cq = tid & 31;
    int rg = tid >> 5;
    float acc[4][4] = {};
    #pragma unroll 8
    for (int k = 0; k < 128; ++k) {
        float4 w = *(const float4*)&Wl[k][cq * 4];
        #pragma unroll
        for (int i = 0; i < 4; ++i) {
            float a = Al[rg * 4 + i][k];
            acc[i][0] = fmaf(a, w.x, acc[i][0]);
            acc[i][1] = fmaf(a, w.y, acc[i][1]);
            acc[i][2] = fmaf(a, w.z, acc[i][2]);
            acc[i][3] = fmaf(a, w.w, acc[i][3]);
        }
    }

    #pragma unroll
    for (int i = 0; i < 4; ++i) {
        size_t r = row0 + rg * 4 + i;
        float4 b = *(const float4*)(bias + cq * 4);
        float4 o = make_float4(acc[i][0] + b.x, acc[i][1] + b.y,
                               acc[i][2] + b.z, acc[i][3] + b.w);
        bfu q0 = f2bf(o.x), q1 = f2bf(o.y), q2 = f2bf(o.z), q3 = f2bf(o.w);
        *(uint2*)(out16 + r * DD + cq * 4) =
            make_uint2((unsigned)q0 | ((unsigned)q1 << 16), (unsigned)q2 | ((unsigned)q3 << 16));
        *(unsigned*)(out8 + r * DD + cq * 4) = pk8(o.x, o.y, o.z, o.w);
    }
}

// ---------------- launch ----------------

extern "C" void kernel_launch(void* const* d_in, const int* in_sizes, int n_in,
                              void* d_out, int out_size, void* d_ws, size_t ws_size,
                              hipStream_t stream) {
    const float* x      = (const float*)d_in[0];
    const int*   eidx   = (const int*)d_in[1];
    const float* emb_w  = (const float*)d_in[3];
    const float* emb_b  = (const float*)d_in[4];
    const float* conv_ws = (const float*)d_in[5];
    const float* conv_b = (const float*)d_in[6];
    const float* ro_w   = (const float*)d_in[7];
    const float* ro_b   = (const float*)d_in[8];

    const int* src = eidx;
    const int* dst = eidx + EE;

    float* y  = (float*)d_out;                   // [N,128] final output
    float* hm = y + (size_t)NN * DD;             // [N,128] h_middle f32 output

    char* p = (char*)d_ws;
    const size_t FB2 = (size_t)NN * DD * sizeof(bfu);   // 25.6 MB
    const size_t FB1 = (size_t)NN * DD;                 // 12.8 MB
    bfu* h16     = (bfu*)p;                 p += FB2;
    bfu* hm16    = (bfu*)p;                 p += FB2;
    unsigned char* h8  = (unsigned char*)p; p += FB1;
    unsigned char* hm8 = (unsigned char*)p; p += FB1;
    unsigned char* bufA8 = (unsigned char*)p; p += FB1;
    unsigned char* bufB8 = (unsigned char*)p; p += FB1;
    float* dinv  = (float*)p;               p += (size_t)NN * 4;
    int* ideg    = (int*)p;                 p += (size_t)NN * 4;
    int* row_ptr = (int*)p;                 p += (size_t)(NN + 1) * 4;
    int* partials = (int*)p;                p += (size_t)512 * 4;
    int* cnt     = (int*)p;                 p += (size_t)NN * NSH * 4;   // 6.4 MB
    int* cur16   = (int*)p;                 p += (size_t)NN * NSH * 4;   // 6.4 MB
    int* bcur    = (int*)p;                 p += (size_t)NBUK * 4;
    uint2* buckets = (uint2*)p;             p += (size_t)NBUK * BCAP * 8; // 14.75 MB
    bfu* Wf      = (bfu*)p;                 p += (size_t)4 * 16384 * sizeof(bfu);
    unsigned* cvp = (unsigned*)p;           p += (size_t)EE * 4;

    const int NB = (NN + 255) / 256;   // 391

    hipMemsetAsync(cnt, 0, (size_t)NN * NSH * 4, stream);
    hipMemsetAsync(bcur, 0, (size_t)NBUK * 4, stream);
    hist_kernel<<<EE / 256, 256, 0, stream>>>(src, dst, cnt, EE);
    offsets_kernel<<<NB, 256, 0, stream>>>(cnt, ideg, dinv, NN);
    partial_sum_kernel<<<NB, 256, 0, stream>>>(ideg, partials, NN);
    scan_partials_kernel<<<1, 512, 0, stream>>>(partials, row_ptr, NB, NN);
    scan_block_kernel<<<NB, 256, 0, stream>>>(ideg, partials, cnt, row_ptr, cur16, NN);
    bucket_scatter_kernel<<<EE / 256, 256, 0, stream>>>(src, dst, dinv, bcur, buckets, EE);
    bucket_place_kernel<<<NBUK, 256, 0, stream>>>(buckets, bcur, cur16, cvp);
    wfrag_kernel<<<4, 256, 0, stream>>>(conv_ws, ro_w, Wf);

    const int MM_GRID   = (NN + 63) / 64;     // 1563
    const int PROP_GRID = NN * 64 / 256;      // 25000

    // h = x @ emb_w + emb_b  (bf16 master + fp8 shadow)
    matmul_f32_kernel<<<NN / 32, 256, 0, stream>>>(x, emb_w, emb_b, h16, h8);

    for (int t = 0; t < 4; ++t) {
        // hm = h + 0.05*tanh(h@W0 + (Ph)@W1 + (P2h)@W2 + b)
        prop_kernel<<<PROP_GRID, 256, 0, stream>>>(h8, bufA8, row_ptr, cvp, NN);
        prop_kernel<<<PROP_GRID, 256, 0, stream>>>(bufA8, bufB8, row_ptr, cvp, NN);
        mfma_mm_kernel<3, true, true><<<MM_GRID, 256, 0, stream>>>(
            h8, bufA8, bufB8, Wf, conv_b, h16,
            (t == 3) ? hm : nullptr, (t == 3) ? hm16 : nullptr, hm8, 0.5f * EPSc);

        // h = h + 0.1*tanh(hm@W0 + (Phm)@W1 + (P2hm)@W2 + b)
        prop_kernel<<<PROP_GRID, 256, 0, stream>>>(hm8, bufA8, row_ptr, cvp, NN);
        prop_kernel<<<PROP_GRID, 256, 0, stream>>>(bufA8, bufB8, row_ptr, cvp, NN);
        mfma_mm_kernel<3, true, true><<<MM_GRID, 256, 0, stream>>>(
            hm8, bufA8, bufB8, Wf, conv_b, h16, nullptr, h16, h8, EPSc);
    }

    // y = h_middle @ ro_w + ro_b  (bf16 A-path for output accuracy)
    mfma_mm_kernel<1, false, false><<<MM_GRID, 256, 0, stream>>>(
        hm16, nullptr, nullptr, Wf + 3 * 16384, ro_b, nullptr, y, nullptr, nullptr, 0.f);
}

// Round 8
// 1635.082 us; speedup vs baseline: 1.2394x; 1.2394x over previous
//
#include <hip/hip_runtime.h>
#include <hip/hip_bf16.h>

#define NN 100000
#define EE 1600000
#define DD 128
#define EPSc 0.1f

typedef unsigned short bfu;
typedef __attribute__((ext_vector_type(8))) short short8;   // 8 bf16 = 4 VGPRs
typedef __attribute__((ext_vector_type(4))) float f32x4;
typedef __attribute__((ext_vector_type(2))) float f32x2;

__device__ __forceinline__ float bf2f(bfu s) {
    union { unsigned u; float f; } c; c.u = ((unsigned)s) << 16; return c.f;
}
__device__ __forceinline__ bfu f2bf(float f) {
    union { float f; unsigned u; } c; c.f = f;
    unsigned u = c.u + 0x7fffu + ((c.u >> 16) & 1u);   // RNE
    return (bfu)(u >> 16);
}
__device__ __forceinline__ unsigned pk8(float a, float b, float c, float d) {
    int r = 0;
    r = __builtin_amdgcn_cvt_pk_fp8_f32(a, b, r, false);
    r = __builtin_amdgcn_cvt_pk_fp8_f32(c, d, r, true);
    return (unsigned)r;
}
__device__ __forceinline__ unsigned char enc8(float a) {
    return (unsigned char)(__builtin_amdgcn_cvt_pk_fp8_f32(a, a, 0, false) & 0xFF);
}
__device__ __forceinline__ short8 e8bf(uint2 u) {
    f32x2 p0 = __builtin_amdgcn_cvt_pk_f32_fp8((int)u.x, false);
    f32x2 p1 = __builtin_amdgcn_cvt_pk_f32_fp8((int)u.x, true);
    f32x2 p2 = __builtin_amdgcn_cvt_pk_f32_fp8((int)u.y, false);
    f32x2 p3 = __builtin_amdgcn_cvt_pk_f32_fp8((int)u.y, true);
    short8 s;
    s[0] = (short)f2bf(p0[0]); s[1] = (short)f2bf(p0[1]);
    s[2] = (short)f2bf(p1[0]); s[3] = (short)f2bf(p1[1]);
    s[4] = (short)f2bf(p2[0]); s[5] = (short)f2bf(p2[1]);
    s[6] = (short)f2bf(p3[0]); s[7] = (short)f2bf(p3[1]);
    return s;
}

// ---------------- CSR build (round-6 structure) ----------------

__global__ __launch_bounds__(256) void count_deg_kernel(const int* __restrict__ dst,
                                                        int* __restrict__ ideg, int e_cnt) {
    int e = blockIdx.x * 256 + threadIdx.x;
    if (e < e_cnt) atomicAdd(&ideg[dst[e]], 1);
}

__global__ __launch_bounds__(256) void dinv_kernel(const int* __restrict__ ideg,
                                                   float* __restrict__ dinv, int n) {
    int i = blockIdx.x * 256 + threadIdx.x;
    if (i < n) {
        int d = ideg[i];
        dinv[i] = (d > 0) ? rsqrtf((float)d) : 0.0f;
    }
}

__global__ __launch_bounds__(256) void partial_sum_kernel(const int* __restrict__ ideg,
                                                          int* __restrict__ partials, int n) {
    __shared__ int sm[256];
    int i = blockIdx.x * 256 + threadIdx.x;
    sm[threadIdx.x] = (i < n) ? ideg[i] : 0;
    __syncthreads();
    for (int off = 128; off > 0; off >>= 1) {
        if ((int)threadIdx.x < off) sm[threadIdx.x] += sm[threadIdx.x + off];
        __syncthreads();
    }
    if (threadIdx.x == 0) partials[blockIdx.x] = sm[0];
}

__global__ __launch_bounds__(512) void scan_partials_kernel(int* __restrict__ partials,
                                                            int* __restrict__ row_ptr,
                                                            int nb, int n) {
    __shared__ int sm[512];
    int v = ((int)threadIdx.x < nb) ? partials[threadIdx.x] : 0;
    sm[threadIdx.x] = v;
    __syncthreads();
    for (int off = 1; off < 512; off <<= 1) {
        int t = (threadIdx.x >= (unsigned)off) ? sm[threadIdx.x - off] : 0;
        __syncthreads();
        sm[threadIdx.x] += t;
        __syncthreads();
    }
    if ((int)threadIdx.x < nb) partials[threadIdx.x] = sm[threadIdx.x] - v;
    if (threadIdx.x == 511) row_ptr[n] = sm[511];
}

__global__ __launch_bounds__(256) void scan_block_kernel(const int* __restrict__ ideg,
                                                         const int* __restrict__ partials,
                                                         int* __restrict__ row_ptr,
                                                         int* __restrict__ cursor, int n) {
    __shared__ int sm[256];
    int i = blockIdx.x * 256 + threadIdx.x;
    int v = (i < n) ? ideg[i] : 0;
    sm[threadIdx.x] = v;
    __syncthreads();
    for (int off = 1; off < 256; off <<= 1) {
        int t = (threadIdx.x >= (unsigned)off) ? sm[threadIdx.x - off] : 0;
        __syncthreads();
        sm[threadIdx.x] += t;
        __syncthreads();
    }
    if (i < n) {
        int excl = partials[blockIdx.x] + sm[threadIdx.x] - v;
        row_ptr[i] = excl;
        cursor[i] = excl;
    }
}

// packed edge: top 15 bits = f32 val bits[31:17] (sign 0), low 17 bits = col
__global__ __launch_bounds__(256) void fill_csr_kernel(const int* __restrict__ src,
                                                       const int* __restrict__ dst,
                                                       const float* __restrict__ dinv,
                                                       int* __restrict__ cursor,
                                                       unsigned* __restrict__ cvp, int e_cnt) {
    int e = blockIdx.x * 256 + threadIdx.x;
    if (e < e_cnt) {
        int d = dst[e], s = src[e];
        int pos = atomicAdd(&cursor[d], 1);
        unsigned vb = __float_as_uint(dinv[s] * dinv[d]);
        unsigned r = vb + 0xFFFFu + ((vb >> 17) & 1u);   // RNE to 15-bit float
        cvp[pos] = (r & 0xFFFE0000u) | (unsigned)s;
    }
}

// ------------- weight -> bf16 MFMA-fragment-order transform -------------

__global__ __launch_bounds__(256) void wfrag_kernel(const float* __restrict__ conv_ws,
                                                    const float* __restrict__ ro_w,
                                                    bfu* __restrict__ Wf) {
    int m = blockIdx.x;   // 0..3
    const float* W = (m < 3) ? conv_ws + m * 16384 : ro_w;
    bfu* T = Wf + m * 16384;
    for (int j = 0; j < 64; ++j) {
        int i = threadIdx.x + j * 256;       // i = k*128 + n
        int k = i >> 7, n = i & 127;
        int nt = n >> 4, ks = k >> 5, kg = (k >> 3) & 3, jj = k & 7;
        int l = kg * 16 + (n & 15);
        int flat = ((nt * 4 + ks) * 64 + l) * 8 + jj;
        T[flat] = f2bf(W[i]);
    }
}

// ---------------- propagation (fp8 in / fp8 out, f32 accum) ----------------
// 8 lanes x 16B per row, 8 edges per gather wavefront-instruction, up to 32
// row-gathers in flight per wave. Edge words coalesced once per 64 edges.

__device__ __forceinline__ void acc16f8(uint4 u, float v, float* acc) {
    f32x2 p0 = __builtin_amdgcn_cvt_pk_f32_fp8((int)u.x, false);
    f32x2 p1 = __builtin_amdgcn_cvt_pk_f32_fp8((int)u.x, true);
    f32x2 p2 = __builtin_amdgcn_cvt_pk_f32_fp8((int)u.y, false);
    f32x2 p3 = __builtin_amdgcn_cvt_pk_f32_fp8((int)u.y, true);
    f32x2 p4 = __builtin_amdgcn_cvt_pk_f32_fp8((int)u.z, false);
    f32x2 p5 = __builtin_amdgcn_cvt_pk_f32_fp8((int)u.z, true);
    f32x2 p6 = __builtin_amdgcn_cvt_pk_f32_fp8((int)u.w, false);
    f32x2 p7 = __builtin_amdgcn_cvt_pk_f32_fp8((int)u.w, true);
    acc[0]  = fmaf(v, p0[0], acc[0]);  acc[1]  = fmaf(v, p0[1], acc[1]);
    acc[2]  = fmaf(v, p1[0], acc[2]);  acc[3]  = fmaf(v, p1[1], acc[3]);
    acc[4]  = fmaf(v, p2[0], acc[4]);  acc[5]  = fmaf(v, p2[1], acc[5]);
    acc[6]  = fmaf(v, p3[0], acc[6]);  acc[7]  = fmaf(v, p3[1], acc[7]);
    acc[8]  = fmaf(v, p4[0], acc[8]);  acc[9]  = fmaf(v, p4[1], acc[9]);
    acc[10] = fmaf(v, p5[0], acc[10]); acc[11] = fmaf(v, p5[1], acc[11]);
    acc[12] = fmaf(v, p6[0], acc[12]); acc[13] = fmaf(v, p6[1], acc[13]);
    acc[14] = fmaf(v, p7[0], acc[14]); acc[15] = fmaf(v, p7[1], acc[15]);
}

__global__ __launch_bounds__(256) void prop_kernel(const unsigned char* __restrict__ xin8,
                                                   unsigned char* __restrict__ out8,
                                                   const int* __restrict__ row_ptr,
                                                   const unsigned* __restrict__ cvp, int n) {
    int wid = (blockIdx.x * 256 + threadIdx.x) >> 6;  // one wave per node
    int lane = threadIdx.x & 63;
    if (wid >= n) return;
    int s = row_ptr[wid];
    int deg = row_ptr[wid + 1] - s;
    int g = lane >> 3;        // edge slot group 0..7
    int li = lane & 7;        // 8 lanes cover 128 fp8 bytes, 16B each
    float acc[16] = {};
    for (int base = 0; base < deg; base += 64) {
        int cnt = deg - base; if (cnt > 64) cnt = 64;
        unsigned el = (lane < cnt) ? cvp[s + base + lane] : 0u;   // coalesced
        for (int q = 0; q < cnt; q += 32) {
            uint4 x[4]; float v[4];
            #pragma unroll
            for (int j = 0; j < 4; ++j) {
                int idx = q + j * 8 + g;
                unsigned c = __shfl(el, idx);
                bool valid = idx < cnt;
                v[j] = valid ? __uint_as_float(c & 0xFFFE0000u) : 0.f;
                x[j] = valid ? *(const uint4*)(xin8 + (size_t)(c & 0x1FFFFu) * DD + li * 16)
                             : make_uint4(0u, 0u, 0u, 0u);
            }
            #pragma unroll
            for (int j = 0; j < 4; ++j) acc16f8(x[j], v[j], acc);
        }
    }
    #pragma unroll
    for (int k = 0; k < 16; ++k) {
        acc[k] += __shfl_xor(acc[k], 8);
        acc[k] += __shfl_xor(acc[k], 16);
        acc[k] += __shfl_xor(acc[k], 32);
    }
    if (g == 0) {
        uint4 q4;
        q4.x = pk8(acc[0],  acc[1],  acc[2],  acc[3]);
        q4.y = pk8(acc[4],  acc[5],  acc[6],  acc[7]);
        q4.z = pk8(acc[8],  acc[9],  acc[10], acc[11]);
        q4.w = pk8(acc[12], acc[13], acc[14], acc[15]);
        *(uint4*)(out8 + (size_t)wid * DD + li * 16) = q4;
    }
}

// ---------------- MFMA matmul: acc = sum_m A_m @ W_m, fused epilogue ----------------

template <int NMAT, bool TANH, bool A8>
__global__ __launch_bounds__(256) void mfma_mm_kernel(const void* __restrict__ A0,
                                                      const void* __restrict__ A1,
                                                      const void* __restrict__ A2,
                                                      const bfu* __restrict__ Wf,
                                                      const float* __restrict__ bias,
                                                      const bfu* __restrict__ base16,
                                                      float* __restrict__ outf,
                                                      bfu* __restrict__ out16,
                                                      unsigned char* __restrict__ out8,
                                                      float scale) {
    int tid = threadIdx.x;
    int wave = tid >> 6, lane = tid & 63;
    int r0 = blockIdx.x * 64 + wave * 16;
    int li = lane & 15, kg = lane >> 4;
    int rowA = r0 + li;
    bool rv = rowA < NN;
    size_t arow = (size_t)(rv ? rowA : 0) * DD;   // elements

    const void* As[3] = {A0, A1, A2};
    short8 a[NMAT][4];
    #pragma unroll
    for (int m = 0; m < NMAT; ++m) {
        #pragma unroll
        for (int ks = 0; ks < 4; ++ks) {
            short8 t;
            if (A8) {
                uint2 u = *(const uint2*)((const unsigned char*)As[m] + arow + ks * 32 + kg * 8);
                t = e8bf(u);
            } else {
                t = *(const short8*)((const bfu*)As[m] + arow + ks * 32 + kg * 8);
            }
            if (!rv) t = (short8)0;
            a[m][ks] = t;
        }
    }

    const short8* Bp = (const short8*)Wf;   // [NMAT][32][64] short8
    f32x4 acc[8];
    #pragma unroll
    for (int nt = 0; nt < 8; ++nt) acc[nt] = (f32x4)(0.f);
    #pragma unroll
    for (int nt = 0; nt < 8; ++nt) {
        #pragma unroll
        for (int m = 0; m < NMAT; ++m) {
            #pragma unroll
            for (int ks = 0; ks < 4; ++ks) {
                short8 b = Bp[m * 2048 + (nt * 4 + ks) * 64 + lane];
                acc[nt] = __builtin_amdgcn_mfma_f32_16x16x32_bf16(a[m][ks], b, acc[nt], 0, 0, 0);
            }
        }
    }

    #pragma unroll
    for (int nt = 0; nt < 8; ++nt) {
        int cc = nt * 16 + li;
        float bv = bias[cc];
        #pragma unroll
        for (int rg = 0; rg < 4; ++rg) {
            int rr = r0 + kg * 4 + rg;
            if (rr < NN) {
                size_t off = (size_t)rr * DD + cc;
                float o = acc[nt][rg];
                if (TANH) {
                    float ov = bf2f(base16[off]) + scale * tanhf(o + bv);
                    if (outf) outf[off] = ov;
                    if (out16) out16[off] = f2bf(ov);
                    out8[off] = enc8(ov);
                } else {
                    outf[off] = o + bv;
                }
            }
        }
    }
}

// ---------------- f32 matmul for embedding: h = x@W + b -> bf16 + fp8 ----------------

__global__ __launch_bounds__(256) void matmul_f32_kernel(const float* __restrict__ A,
                                                         const float* __restrict__ W,
                                                         const float* __restrict__ bias,
                                                         bfu* __restrict__ out16,
                                                         unsigned char* __restrict__ out8) {
    __shared__ float Wl[128][128];
    __shared__ float Al[32][128];
    int tid = threadIdx.x;

    const float4* Wv = (const float4*)W;
    float4* Wlv = (float4*)&Wl[0][0];
    #pragma unroll
    for (int i = 0; i < 16; ++i) Wlv[tid + i * 256] = Wv[tid + i * 256];

    size_t row0 = (size_t)blockIdx.x * 32;
    const float4* Av = (const float4*)(A + row0 * DD);
    float4* Alv = (float4*)&Al[0][0];
    #pragma unroll
    for (int i = 0; i < 4; ++i) Alv[tid + i * 256] = Av[tid + i * 256];
    __syncthreads();

    int cq = tid & 31;
    int rg = tid >> 5;
    float acc[4][4] = {};
    #pragma unroll 8
    for (int k = 0; k < 128; ++k) {
        float4 w = *(const float4*)&Wl[k][cq * 4];
        #pragma unroll
        for (int i = 0; i < 4; ++i) {
            float a = Al[rg * 4 + i][k];
            acc[i][0] = fmaf(a, w.x, acc[i][0]);
            acc[i][1] = fmaf(a, w.y, acc[i][1]);
            acc[i][2] = fmaf(a, w.z, acc[i][2]);
            acc[i][3] = fmaf(a, w.w, acc[i][3]);
        }
    }

    #pragma unroll
    for (int i = 0; i < 4; ++i) {
        size_t r = row0 + rg * 4 + i;
        float4 b = *(const float4*)(bias + cq * 4);
        float4 o = make_float4(acc[i][0] + b.x, acc[i][1] + b.y,
                               acc[i][2] + b.z, acc[i][3] + b.w);
        bfu q0 = f2bf(o.x), q1 = f2bf(o.y), q2 = f2bf(o.z), q3 = f2bf(o.w);
        *(uint2*)(out16 + r * DD + cq * 4) =
            make_uint2((unsigned)q0 | ((unsigned)q1 << 16), (unsigned)q2 | ((unsigned)q3 << 16));
        *(unsigned*)(out8 + r * DD + cq * 4) = pk8(o.x, o.y, o.z, o.w);
    }
}

// ---------------- launch ----------------

extern "C" void kernel_launch(void* const* d_in, const int* in_sizes, int n_in,
                              void* d_out, int out_size, void* d_ws, size_t ws_size,
                              hipStream_t stream) {
    const float* x      = (const float*)d_in[0];
    const int*   eidx   = (const int*)d_in[1];
    const float* emb_w  = (const float*)d_in[3];
    const float* emb_b  = (const float*)d_in[4];
    const float* conv_ws = (const float*)d_in[5];
    const float* conv_b = (const float*)d_in[6];
    const float* ro_w   = (const float*)d_in[7];
    const float* ro_b   = (const float*)d_in[8];

    const int* src = eidx;
    const int* dst = eidx + EE;

    float* y  = (float*)d_out;                   // [N,128] final output
    float* hm = y + (size_t)NN * DD;             // [N,128] h_middle f32 output

    char* p = (char*)d_ws;
    const size_t FB2 = (size_t)NN * DD * sizeof(bfu);   // 25.6 MB
    const size_t FB1 = (size_t)NN * DD;                 // 12.8 MB
    bfu* h16     = (bfu*)p;                 p += FB2;   // bf16 master state
    bfu* hm16    = (bfu*)p;                 p += FB2;   // bf16 h_middle (t==3 only)
    unsigned char* h8  = (unsigned char*)p; p += FB1;
    unsigned char* hm8 = (unsigned char*)p; p += FB1;
    unsigned char* bufA8 = (unsigned char*)p; p += FB1;
    unsigned char* bufB8 = (unsigned char*)p; p += FB1;
    float* dinv  = (float*)p;               p += (size_t)NN * 4;
    int* ideg    = (int*)p;                 p += (size_t)NN * 4;
    int* row_ptr = (int*)p;                 p += (size_t)(NN + 1) * 4;
    int* cursor  = (int*)p;                 p += (size_t)NN * 4;
    int* partials = (int*)p;                p += (size_t)512 * 4;
    bfu* Wf      = (bfu*)p;                 p += (size_t)4 * 16384 * sizeof(bfu);
    unsigned* cvp = (unsigned*)p;           p += (size_t)EE * 4;

    const int NB = (NN + 255) / 256;   // 391

    hipMemsetAsync(ideg, 0, (size_t)NN * 4, stream);
    count_deg_kernel<<<EE / 256, 256, 0, stream>>>(dst, ideg, EE);
    dinv_kernel<<<NB, 256, 0, stream>>>(ideg, dinv, NN);
    partial_sum_kernel<<<NB, 256, 0, stream>>>(ideg, partials, NN);
    scan_partials_kernel<<<1, 512, 0, stream>>>(partials, row_ptr, NB, NN);
    scan_block_kernel<<<NB, 256, 0, stream>>>(ideg, partials, row_ptr, cursor, NN);
    fill_csr_kernel<<<EE / 256, 256, 0, stream>>>(src, dst, dinv, cursor, cvp, EE);
    wfrag_kernel<<<4, 256, 0, stream>>>(conv_ws, ro_w, Wf);

    const int MM_GRID   = (NN + 63) / 64;     // 1563
    const int PROP_GRID = NN * 64 / 256;      // 25000

    // h = x @ emb_w + emb_b  (bf16 master + fp8 shadow)
    matmul_f32_kernel<<<NN / 32, 256, 0, stream>>>(x, emb_w, emb_b, h16, h8);

    for (int t = 0; t < 4; ++t) {
        // hm = h + 0.05*tanh(h@W0 + (Ph)@W1 + (P2h)@W2 + b)
        prop_kernel<<<PROP_GRID, 256, 0, stream>>>(h8, bufA8, row_ptr, cvp, NN);
        prop_kernel<<<PROP_GRID, 256, 0, stream>>>(bufA8, bufB8, row_ptr, cvp, NN);
        mfma_mm_kernel<3, true, true><<<MM_GRID, 256, 0, stream>>>(
            h8, bufA8, bufB8, Wf, conv_b, h16,
            (t == 3) ? hm : nullptr, (t == 3) ? hm16 : nullptr, hm8, 0.5f * EPSc);

        // h = h + 0.1*tanh(hm@W0 + (Phm)@W1 + (P2hm)@W2 + b)
        prop_kernel<<<PROP_GRID, 256, 0, stream>>>(hm8, bufA8, row_ptr, cvp, NN);
        prop_kernel<<<PROP_GRID, 256, 0, stream>>>(bufA8, bufB8, row_ptr, cvp, NN);
        mfma_mm_kernel<3, true, true><<<MM_GRID, 256, 0, stream>>>(
            hm8, bufA8, bufB8, Wf, conv_b, h16, nullptr, h16, h8, EPSc);
    }

    // y = h_middle @ ro_w + ro_b  (bf16 A-path for output accuracy)
    mfma_mm_kernel<1, false, false><<<MM_GRID, 256, 0, stream>>>(
        hm16, nullptr, nullptr, Wf + 3 * 16384, ro_b, nullptr, y, nullptr, nullptr, 0.f);
}

// Round 9
// 1461.373 us; speedup vs baseline: 1.3867x; 1.1189x over previous
//
#include <hip/hip_runtime.h>
#include <hip/hip_bf16.h>

#define NN 100000
#define EE 1600000
#define DD 128
#define EPSc 0.1f

typedef unsigned short bfu;
typedef __attribute__((ext_vector_type(8))) short short8;   // 8 bf16 = 4 VGPRs
typedef __attribute__((ext_vector_type(4))) float f32x4;
typedef __attribute__((ext_vector_type(2))) float f32x2;

__device__ __forceinline__ float bf2f(bfu s) {
    union { unsigned u; float f; } c; c.u = ((unsigned)s) << 16; return c.f;
}
__device__ __forceinline__ bfu f2bf(float f) {
    union { float f; unsigned u; } c; c.f = f;
    unsigned u = c.u + 0x7fffu + ((c.u >> 16) & 1u);   // RNE
    return (bfu)(u >> 16);
}
__device__ __forceinline__ unsigned pk8(float a, float b, float c, float d) {
    int r = 0;
    r = __builtin_amdgcn_cvt_pk_fp8_f32(a, b, r, false);
    r = __builtin_amdgcn_cvt_pk_fp8_f32(c, d, r, true);
    return (unsigned)r;
}
__device__ __forceinline__ unsigned char enc8(float a) {
    return (unsigned char)(__builtin_amdgcn_cvt_pk_fp8_f32(a, a, 0, false) & 0xFF);
}
__device__ __forceinline__ short8 e8bf(uint2 u) {
    f32x2 p0 = __builtin_amdgcn_cvt_pk_f32_fp8((int)u.x, false);
    f32x2 p1 = __builtin_amdgcn_cvt_pk_f32_fp8((int)u.x, true);
    f32x2 p2 = __builtin_amdgcn_cvt_pk_f32_fp8((int)u.y, false);
    f32x2 p3 = __builtin_amdgcn_cvt_pk_f32_fp8((int)u.y, true);
    short8 s;
    s[0] = (short)f2bf(p0[0]); s[1] = (short)f2bf(p0[1]);
    s[2] = (short)f2bf(p1[0]); s[3] = (short)f2bf(p1[1]);
    s[4] = (short)f2bf(p2[0]); s[5] = (short)f2bf(p2[1]);
    s[6] = (short)f2bf(p3[0]); s[7] = (short)f2bf(p3[1]);
    return s;
}
// fast tanh: (e^{2x}-1)/(e^{2x}+1), clamped so exp can't overflow
__device__ __forceinline__ float ftanh(float x) {
    float xc = fminf(fmaxf(x, -9.0f), 9.0f);
    float e = __expf(2.0f * xc);
    return (e - 1.0f) * __builtin_amdgcn_rcpf(e + 1.0f);
}

// ---------------- CSR build ----------------

__global__ __launch_bounds__(256) void count_deg_kernel(const int* __restrict__ dst,
                                                        int* __restrict__ ideg, int e_cnt) {
    int e = blockIdx.x * 256 + threadIdx.x;
    if (e < e_cnt) atomicAdd(&ideg[dst[e]], 1);
}

__global__ __launch_bounds__(256) void dinv_kernel(const int* __restrict__ ideg,
                                                   float* __restrict__ dinv, int n) {
    int i = blockIdx.x * 256 + threadIdx.x;
    if (i < n) {
        int d = ideg[i];
        dinv[i] = (d > 0) ? rsqrtf((float)d) : 0.0f;
    }
}

__global__ __launch_bounds__(256) void partial_sum_kernel(const int* __restrict__ ideg,
                                                          int* __restrict__ partials, int n) {
    __shared__ int sm[256];
    int i = blockIdx.x * 256 + threadIdx.x;
    sm[threadIdx.x] = (i < n) ? ideg[i] : 0;
    __syncthreads();
    for (int off = 128; off > 0; off >>= 1) {
        if ((int)threadIdx.x < off) sm[threadIdx.x] += sm[threadIdx.x + off];
        __syncthreads();
    }
    if (threadIdx.x == 0) partials[blockIdx.x] = sm[0];
}

__global__ __launch_bounds__(512) void scan_partials_kernel(int* __restrict__ partials,
                                                            int* __restrict__ row_ptr,
                                                            int nb, int n) {
    __shared__ int sm[512];
    int v = ((int)threadIdx.x < nb) ? partials[threadIdx.x] : 0;
    sm[threadIdx.x] = v;
    __syncthreads();
    for (int off = 1; off < 512; off <<= 1) {
        int t = (threadIdx.x >= (unsigned)off) ? sm[threadIdx.x - off] : 0;
        __syncthreads();
        sm[threadIdx.x] += t;
        __syncthreads();
    }
    if ((int)threadIdx.x < nb) partials[threadIdx.x] = sm[threadIdx.x] - v;
    if (threadIdx.x == 511) row_ptr[n] = sm[511];
}

__global__ __launch_bounds__(256) void scan_block_kernel(const int* __restrict__ ideg,
                                                         const int* __restrict__ partials,
                                                         int* __restrict__ row_ptr,
                                                         int* __restrict__ cursor, int n) {
    __shared__ int sm[256];
    int i = blockIdx.x * 256 + threadIdx.x;
    int v = (i < n) ? ideg[i] : 0;
    sm[threadIdx.x] = v;
    __syncthreads();
    for (int off = 1; off < 256; off <<= 1) {
        int t = (threadIdx.x >= (unsigned)off) ? sm[threadIdx.x - off] : 0;
        __syncthreads();
        sm[threadIdx.x] += t;
        __syncthreads();
    }
    if (i < n) {
        int excl = partials[blockIdx.x] + sm[threadIdx.x] - v;
        row_ptr[i] = excl;
        cursor[i] = excl;
    }
}

// packed edge: top 15 bits = f32 val bits[31:17] (sign 0), low 17 bits = col
__global__ __launch_bounds__(256) void fill_csr_kernel(const int* __restrict__ src,
                                                       const int* __restrict__ dst,
                                                       const float* __restrict__ dinv,
                                                       int* __restrict__ cursor,
                                                       unsigned* __restrict__ cvp, int e_cnt) {
    int e = blockIdx.x * 256 + threadIdx.x;
    if (e < e_cnt) {
        int d = dst[e], s = src[e];
        int pos = atomicAdd(&cursor[d], 1);
        unsigned vb = __float_as_uint(dinv[s] * dinv[d]);
        unsigned r = vb + 0xFFFFu + ((vb >> 17) & 1u);   // RNE to 15-bit float
        cvp[pos] = (r & 0xFFFE0000u) | (unsigned)s;
    }
}

// ------------- weight -> bf16 MFMA-fragment-order transform -------------

__global__ __launch_bounds__(256) void wfrag_kernel(const float* __restrict__ conv_ws,
                                                    const float* __restrict__ ro_w,
                                                    bfu* __restrict__ Wf) {
    int m = blockIdx.x;   // 0..3
    const float* W = (m < 3) ? conv_ws + m * 16384 : ro_w;
    bfu* T = Wf + m * 16384;
    for (int j = 0; j < 64; ++j) {
        int i = threadIdx.x + j * 256;       // i = k*128 + n
        int k = i >> 7, n = i & 127;
        int nt = n >> 4, ks = k >> 5, kg = (k >> 3) & 3, jj = k & 7;
        int l = kg * 16 + (n & 15);
        int flat = ((nt * 4 + ks) * 64 + l) * 8 + jj;
        T[flat] = f2bf(W[i]);
    }
}

// ---------------- propagation (round-6 verbatim: fp8 in/out, f32 accum) ----------------

__device__ __forceinline__ void acc8f8(uint2 u, float v, float* acc) {
    f32x2 p0 = __builtin_amdgcn_cvt_pk_f32_fp8((int)u.x, false);
    f32x2 p1 = __builtin_amdgcn_cvt_pk_f32_fp8((int)u.x, true);
    f32x2 p2 = __builtin_amdgcn_cvt_pk_f32_fp8((int)u.y, false);
    f32x2 p3 = __builtin_amdgcn_cvt_pk_f32_fp8((int)u.y, true);
    acc[0] = fmaf(v, p0[0], acc[0]); acc[1] = fmaf(v, p0[1], acc[1]);
    acc[2] = fmaf(v, p1[0], acc[2]); acc[3] = fmaf(v, p1[1], acc[3]);
    acc[4] = fmaf(v, p2[0], acc[4]); acc[5] = fmaf(v, p2[1], acc[5]);
    acc[6] = fmaf(v, p3[0], acc[6]); acc[7] = fmaf(v, p3[1], acc[7]);
}

__global__ __launch_bounds__(256) void prop_kernel(const unsigned char* __restrict__ xin8,
                                                   unsigned char* __restrict__ out8,
                                                   const int* __restrict__ row_ptr,
                                                   const unsigned* __restrict__ cvp, int n) {
    int wid = (blockIdx.x * 256 + threadIdx.x) >> 6;  // one wave per node
    int lane = threadIdx.x & 63;
    if (wid >= n) return;
    int s = row_ptr[wid];
    int deg = row_ptr[wid + 1] - s;
    int g = lane >> 4;        // edge slot group 0..3
    int li = lane & 15;       // 16 lanes cover 128 dims (8 fp8 bytes each)
    float acc[8] = {0.f, 0.f, 0.f, 0.f, 0.f, 0.f, 0.f, 0.f};
    for (int base = 0; base < deg; base += 64) {
        int cnt = deg - base; if (cnt > 64) cnt = 64;
        unsigned el = (lane < cnt) ? cvp[s + base + lane] : 0u;   // coalesced
        for (int q = 0; q < cnt; q += 16) {
            uint2 x[4]; float v[4];
            #pragma unroll
            for (int j = 0; j < 4; ++j) {
                int idx = q + j * 4 + g;
                unsigned c = __shfl(el, idx);
                bool valid = idx < cnt;
                v[j] = valid ? __uint_as_float(c & 0xFFFE0000u) : 0.f;
                x[j] = valid ? *(const uint2*)(xin8 + (size_t)(c & 0x1FFFFu) * DD + li * 8)
                             : make_uint2(0u, 0u);
            }
            #pragma unroll
            for (int j = 0; j < 4; ++j) acc8f8(x[j], v[j], acc);
        }
    }
    #pragma unroll
    for (int k = 0; k < 8; ++k) {
        acc[k] += __shfl_xor(acc[k], 16);
        acc[k] += __shfl_xor(acc[k], 32);
    }
    if (g == 0) {
        uint2 q;
        q.x = pk8(acc[0], acc[1], acc[2], acc[3]);
        q.y = pk8(acc[4], acc[5], acc[6], acc[7]);
        *(uint2*)(out8 + (size_t)wid * DD + li * 8) = q;
    }
}

// ---------------- MFMA matmul: acc = sum_m A_m @ W_m, fused epilogue ----------------
// 32 rows per wave (two 16-row A-sets share every loaded B fragment -> half B traffic)

template <int NMAT, bool TANH, bool A8>
__global__ __launch_bounds__(256, 2) void mfma_mm_kernel(const void* __restrict__ A0,
                                                         const void* __restrict__ A1,
                                                         const void* __restrict__ A2,
                                                         const bfu* __restrict__ Wf,
                                                         const float* __restrict__ bias,
                                                         const bfu* __restrict__ base16,
                                                         float* __restrict__ outf,
                                                         bfu* __restrict__ out16,
                                                         unsigned char* __restrict__ out8,
                                                         float scale) {
    int tid = threadIdx.x;
    int wave = tid >> 6, lane = tid & 63;
    int r0 = blockIdx.x * 128 + wave * 32;     // 32 rows per wave
    int li = lane & 15, kg = lane >> 4;

    const void* As[3] = {A0, A1, A2};
    short8 a[2][NMAT][4];
    #pragma unroll
    for (int sset = 0; sset < 2; ++sset) {
        int rowA = r0 + sset * 16 + li;
        bool rv = rowA < NN;
        size_t arow = (size_t)(rv ? rowA : 0) * DD;
        #pragma unroll
        for (int m = 0; m < NMAT; ++m) {
            #pragma unroll
            for (int ks = 0; ks < 4; ++ks) {
                short8 t;
                if (A8) {
                    uint2 u = *(const uint2*)((const unsigned char*)As[m] + arow + ks * 32 + kg * 8);
                    t = e8bf(u);
                } else {
                    t = *(const short8*)((const bfu*)As[m] + arow + ks * 32 + kg * 8);
                }
                if (!rv) t = (short8)0;
                a[sset][m][ks] = t;
            }
        }
    }

    const short8* Bp = (const short8*)Wf;   // [NMAT][32][64] short8
    f32x4 acc[2][8];
    #pragma unroll
    for (int sset = 0; sset < 2; ++sset)
        #pragma unroll
        for (int nt = 0; nt < 8; ++nt) acc[sset][nt] = (f32x4)(0.f);

    #pragma unroll
    for (int nt = 0; nt < 8; ++nt) {
        #pragma unroll
        for (int m = 0; m < NMAT; ++m) {
            #pragma unroll
            for (int ks = 0; ks < 4; ++ks) {
                short8 b = Bp[m * 2048 + (nt * 4 + ks) * 64 + lane];
                acc[0][nt] = __builtin_amdgcn_mfma_f32_16x16x32_bf16(a[0][m][ks], b, acc[0][nt], 0, 0, 0);
                acc[1][nt] = __builtin_amdgcn_mfma_f32_16x16x32_bf16(a[1][m][ks], b, acc[1][nt], 0, 0, 0);
            }
        }
    }

    #pragma unroll
    for (int sset = 0; sset < 2; ++sset) {
        #pragma unroll
        for (int nt = 0; nt < 8; ++nt) {
            int cc = nt * 16 + li;
            float bv = bias[cc];
            #pragma unroll
            for (int rg = 0; rg < 4; ++rg) {
                int rr = r0 + sset * 16 + kg * 4 + rg;
                if (rr < NN) {
                    size_t off = (size_t)rr * DD + cc;
                    float o = acc[sset][nt][rg];
                    if (TANH) {
                        float ov = bf2f(base16[off]) + scale * ftanh(o + bv);
                        if (outf) outf[off] = ov;
                        if (out16) out16[off] = f2bf(ov);
                        out8[off] = enc8(ov);
                    } else {
                        outf[off] = o + bv;
                    }
                }
            }
        }
    }
}

// ---------------- f32 matmul for embedding: h = x@W + b -> bf16 + fp8 ----------------

__global__ __launch_bounds__(256) void matmul_f32_kernel(const float* __restrict__ A,
                                                         const float* __restrict__ W,
                                                         const float* __restrict__ bias,
                                                         bfu* __restrict__ out16,
                                                         unsigned char* __restrict__ out8) {
    __shared__ float Wl[128][128];
    __shared__ float Al[32][128];
    int tid = threadIdx.x;

    const float4* Wv = (const float4*)W;
    float4* Wlv = (float4*)&Wl[0][0];
    #pragma unroll
    for (int i = 0; i < 16; ++i) Wlv[tid + i * 256] = Wv[tid + i * 256];

    size_t row0 = (size_t)blockIdx.x * 32;
    const float4* Av = (const float4*)(A + row0 * DD);
    float4* Alv = (float4*)&Al[0][0];
    #pragma unroll
    for (int i = 0; i < 4; ++i) Alv[tid + i * 256] = Av[tid + i * 256];
    __syncthreads();

    int cq = tid & 31;
    int rg = tid >> 5;
    float acc[4][4] = {};
    #pragma unroll 8
    for (int k = 0; k < 128; ++k) {
        float4 w = *(const float4*)&Wl[k][cq * 4];
        #pragma unroll
        for (int i = 0; i < 4; ++i) {
            float a = Al[rg * 4 + i][k];
            acc[i][0] = fmaf(a, w.x, acc[i][0]);
            acc[i][1] = fmaf(a, w.y, acc[i][1]);
            acc[i][2] = fmaf(a, w.z, acc[i][2]);
            acc[i][3] = fmaf(a, w.w, acc[i][3]);
        }
    }

    #pragma unroll
    for (int i = 0; i < 4; ++i) {
        size_t r = row0 + rg * 4 + i;
        float4 b = *(const float4*)(bias + cq * 4);
        float4 o = make_float4(acc[i][0] + b.x, acc[i][1] + b.y,
                               acc[i][2] + b.z, acc[i][3] + b.w);
        bfu q0 = f2bf(o.x), q1 = f2bf(o.y), q2 = f2bf(o.z), q3 = f2bf(o.w);
        *(uint2*)(out16 + r * DD + cq * 4) =
            make_uint2((unsigned)q0 | ((unsigned)q1 << 16), (unsigned)q2 | ((unsigned)q3 << 16));
        *(unsigned*)(out8 + r * DD + cq * 4) = pk8(o.x, o.y, o.z, o.w);
    }
}

// ---------------- launch ----------------

extern "C" void kernel_launch(void* const* d_in, const int* in_sizes, int n_in,
                              void* d_out, int out_size, void* d_ws, size_t ws_size,
                              hipStream_t stream) {
    const float* x      = (const float*)d_in[0];
    const int*   eidx   = (const int*)d_in[1];
    const float* emb_w  = (const float*)d_in[3];
    const float* emb_b  = (const float*)d_in[4];
    const float* conv_ws = (const float*)d_in[5];
    const float* conv_b = (const float*)d_in[6];
    const float* ro_w   = (const float*)d_in[7];
    const float* ro_b   = (const float*)d_in[8];

    const int* src = eidx;
    const int* dst = eidx + EE;

    float* y  = (float*)d_out;                   // [N,128] final output
    float* hm = y + (size_t)NN * DD;             // [N,128] h_middle f32 output

    char* p = (char*)d_ws;
    const size_t FB2 = (size_t)NN * DD * sizeof(bfu);   // 25.6 MB
    const size_t FB1 = (size_t)NN * DD;                 // 12.8 MB
    bfu* h16     = (bfu*)p;                 p += FB2;   // bf16 master state
    bfu* hm16    = (bfu*)p;                 p += FB2;   // bf16 h_middle (t==3 only)
    unsigned char* h8  = (unsigned char*)p; p += FB1;
    unsigned char* hm8 = (unsigned char*)p; p += FB1;
    unsigned char* bufA8 = (unsigned char*)p; p += FB1;
    unsigned char* bufB8 = (unsigned char*)p; p += FB1;
    float* dinv  = (float*)p;               p += (size_t)NN * 4;
    int* ideg    = (int*)p;                 p += (size_t)NN * 4;
    int* row_ptr = (int*)p;                 p += (size_t)(NN + 1) * 4;
    int* cursor  = (int*)p;                 p += (size_t)NN * 4;
    int* partials = (int*)p;                p += (size_t)512 * 4;
    bfu* Wf      = (bfu*)p;                 p += (size_t)4 * 16384 * sizeof(bfu);
    unsigned* cvp = (unsigned*)p;           p += (size_t)EE * 4;

    const int NB = (NN + 255) / 256;   // 391

    hipMemsetAsync(ideg, 0, (size_t)NN * 4, stream);
    count_deg_kernel<<<EE / 256, 256, 0, stream>>>(dst, ideg, EE);
    dinv_kernel<<<NB, 256, 0, stream>>>(ideg, dinv, NN);
    partial_sum_kernel<<<NB, 256, 0, stream>>>(ideg, partials, NN);
    scan_partials_kernel<<<1, 512, 0, stream>>>(partials, row_ptr, NB, NN);
    scan_block_kernel<<<NB, 256, 0, stream>>>(ideg, partials, row_ptr, cursor, NN);
    fill_csr_kernel<<<EE / 256, 256, 0, stream>>>(src, dst, dinv, cursor, cvp, EE);
    wfrag_kernel<<<4, 256, 0, stream>>>(conv_ws, ro_w, Wf);

    const int MM_GRID   = (NN + 127) / 128;   // 782 (32 rows/wave, 4 waves/block)
    const int PROP_GRID = NN * 64 / 256;      // 25000

    // h = x @ emb_w + emb_b  (bf16 master + fp8 shadow)
    matmul_f32_kernel<<<NN / 32, 256, 0, stream>>>(x, emb_w, emb_b, h16, h8);

    for (int t = 0; t < 4; ++t) {
        // hm = h + 0.05*tanh(h@W0 + (Ph)@W1 + (P2h)@W2 + b)
        prop_kernel<<<PROP_GRID, 256, 0, stream>>>(h8, bufA8, row_ptr, cvp, NN);
        prop_kernel<<<PROP_GRID, 256, 0, stream>>>(bufA8, bufB8, row_ptr, cvp, NN);
        mfma_mm_kernel<3, true, true><<<MM_GRID, 256, 0, stream>>>(
            h8, bufA8, bufB8, Wf, conv_b, h16,
            (t == 3) ? hm : nullptr, (t == 3) ? hm16 : nullptr, hm8, 0.5f * EPSc);

        // h = h + 0.1*tanh(hm@W0 + (Phm)@W1 + (P2hm)@W2 + b)
        prop_kernel<<<PROP_GRID, 256, 0, stream>>>(hm8, bufA8, row_ptr, cvp, NN);
        prop_kernel<<<PROP_GRID, 256, 0, stream>>>(bufA8, bufB8, row_ptr, cvp, NN);
        mfma_mm_kernel<3, true, true><<<MM_GRID, 256, 0, stream>>>(
            hm8, bufA8, bufB8, Wf, conv_b, h16, nullptr, h16, h8, EPSc);
    }

    // y = h_middle @ ro_w + ro_b  (bf16 A-path for output accuracy)
    mfma_mm_kernel<1, false, false><<<MM_GRID, 256, 0, stream>>>(
        hm16, nullptr, nullptr, Wf + 3 * 16384, ro_b, nullptr, y, nullptr, nullptr, 0.f);
}

// Round 10
// 1140.959 us; speedup vs baseline: 1.7762x; 1.2808x over previous
//
#include <hip/hip_runtime.h>
#include <hip/hip_bf16.h>

#define NN 100000
#define EE 1600000
#define DD 128
#define EPSc 0.1f

typedef unsigned short bfu;
typedef __attribute__((ext_vector_type(8))) short short8;   // 8 bf16 = 4 VGPRs
typedef __attribute__((ext_vector_type(4))) float f32x4;
typedef __attribute__((ext_vector_type(2))) float f32x2;

__device__ __forceinline__ float bf2f(bfu s) {
    union { unsigned u; float f; } c; c.u = ((unsigned)s) << 16; return c.f;
}
__device__ __forceinline__ bfu f2bf(float f) {
    union { float f; unsigned u; } c; c.f = f;
    unsigned u = c.u + 0x7fffu + ((c.u >> 16) & 1u);   // RNE
    return (bfu)(u >> 16);
}
__device__ __forceinline__ unsigned pk8(float a, float b, float c, float d) {
    int r = 0;
    r = __builtin_amdgcn_cvt_pk_fp8_f32(a, b, r, false);
    r = __builtin_amdgcn_cvt_pk_fp8_f32(c, d, r, true);
    return (unsigned)r;
}
__device__ __forceinline__ unsigned char enc8(float a) {
    return (unsigned char)(__builtin_amdgcn_cvt_pk_fp8_f32(a, a, 0, false) & 0xFF);
}
__device__ __forceinline__ short8 e8bf(uint2 u) {
    f32x2 p0 = __builtin_amdgcn_cvt_pk_f32_fp8((int)u.x, false);
    f32x2 p1 = __builtin_amdgcn_cvt_pk_f32_fp8((int)u.x, true);
    f32x2 p2 = __builtin_amdgcn_cvt_pk_f32_fp8((int)u.y, false);
    f32x2 p3 = __builtin_amdgcn_cvt_pk_f32_fp8((int)u.y, true);
    short8 s;
    s[0] = (short)f2bf(p0[0]); s[1] = (short)f2bf(p0[1]);
    s[2] = (short)f2bf(p1[0]); s[3] = (short)f2bf(p1[1]);
    s[4] = (short)f2bf(p2[0]); s[5] = (short)f2bf(p2[1]);
    s[6] = (short)f2bf(p3[0]); s[7] = (short)f2bf(p3[1]);
    return s;
}
// fast tanh: (e^{2x}-1)/(e^{2x}+1), clamped so exp can't overflow
__device__ __forceinline__ float ftanh(float x) {
    float xc = fminf(fmaxf(x, -9.0f), 9.0f);
    float e = __expf(2.0f * xc);
    return (e - 1.0f) * __builtin_amdgcn_rcpf(e + 1.0f);
}

// ---------------- CSR build ----------------

__global__ __launch_bounds__(256) void count_deg_kernel(const int* __restrict__ dst,
                                                        int* __restrict__ ideg, int e_cnt) {
    int e = blockIdx.x * 256 + threadIdx.x;
    if (e < e_cnt) atomicAdd(&ideg[dst[e]], 1);
}

__global__ __launch_bounds__(256) void dinv_kernel(const int* __restrict__ ideg,
                                                   float* __restrict__ dinv, int n) {
    int i = blockIdx.x * 256 + threadIdx.x;
    if (i < n) {
        int d = ideg[i];
        dinv[i] = (d > 0) ? rsqrtf((float)d) : 0.0f;
    }
}

__global__ __launch_bounds__(256) void partial_sum_kernel(const int* __restrict__ ideg,
                                                          int* __restrict__ partials, int n) {
    __shared__ int sm[256];
    int i = blockIdx.x * 256 + threadIdx.x;
    sm[threadIdx.x] = (i < n) ? ideg[i] : 0;
    __syncthreads();
    for (int off = 128; off > 0; off >>= 1) {
        if ((int)threadIdx.x < off) sm[threadIdx.x] += sm[threadIdx.x + off];
        __syncthreads();
    }
    if (threadIdx.x == 0) partials[blockIdx.x] = sm[0];
}

__global__ __launch_bounds__(512) void scan_partials_kernel(int* __restrict__ partials,
                                                            int* __restrict__ row_ptr,
                                                            int nb, int n) {
    __shared__ int sm[512];
    int v = ((int)threadIdx.x < nb) ? partials[threadIdx.x] : 0;
    sm[threadIdx.x] = v;
    __syncthreads();
    for (int off = 1; off < 512; off <<= 1) {
        int t = (threadIdx.x >= (unsigned)off) ? sm[threadIdx.x - off] : 0;
        __syncthreads();
        sm[threadIdx.x] += t;
        __syncthreads();
    }
    if ((int)threadIdx.x < nb) partials[threadIdx.x] = sm[threadIdx.x] - v;
    if (threadIdx.x == 511) row_ptr[n] = sm[511];
}

__global__ __launch_bounds__(256) void scan_block_kernel(const int* __restrict__ ideg,
                                                         const int* __restrict__ partials,
                                                         int* __restrict__ row_ptr,
                                                         int* __restrict__ cursor, int n) {
    __shared__ int sm[256];
    int i = blockIdx.x * 256 + threadIdx.x;
    int v = (i < n) ? ideg[i] : 0;
    sm[threadIdx.x] = v;
    __syncthreads();
    for (int off = 1; off < 256; off <<= 1) {
        int t = (threadIdx.x >= (unsigned)off) ? sm[threadIdx.x - off] : 0;
        __syncthreads();
        sm[threadIdx.x] += t;
        __syncthreads();
    }
    if (i < n) {
        int excl = partials[blockIdx.x] + sm[threadIdx.x] - v;
        row_ptr[i] = excl;
        cursor[i] = excl;
    }
}

// packed edge: top 15 bits = f32 val bits[31:17] (sign 0), low 17 bits = col
__global__ __launch_bounds__(256) void fill_csr_kernel(const int* __restrict__ src,
                                                       const int* __restrict__ dst,
                                                       const float* __restrict__ dinv,
                                                       int* __restrict__ cursor,
                                                       unsigned* __restrict__ cvp, int e_cnt) {
    int e = blockIdx.x * 256 + threadIdx.x;
    if (e < e_cnt) {
        int d = dst[e], s = src[e];
        int pos = atomicAdd(&cursor[d], 1);
        unsigned vb = __float_as_uint(dinv[s] * dinv[d]);
        unsigned r = vb + 0xFFFFu + ((vb >> 17) & 1u);   // RNE to 15-bit float
        cvp[pos] = (r & 0xFFFE0000u) | (unsigned)s;
    }
}

// ------------- weight -> bf16 MFMA-fragment-order transform -------------

__global__ __launch_bounds__(256) void wfrag_kernel(const float* __restrict__ conv_ws,
                                                    const float* __restrict__ ro_w,
                                                    bfu* __restrict__ Wf) {
    int m = blockIdx.x;   // 0..3
    const float* W = (m < 3) ? conv_ws + m * 16384 : ro_w;
    bfu* T = Wf + m * 16384;
    for (int j = 0; j < 64; ++j) {
        int i = threadIdx.x + j * 256;       // i = k*128 + n
        int k = i >> 7, n = i & 127;
        int nt = n >> 4, ks = k >> 5, kg = (k >> 3) & 3, jj = k & 7;
        int l = kg * 16 + (n & 15);
        int flat = ((nt * 4 + ks) * 64 + l) * 8 + jj;
        T[flat] = f2bf(W[i]);
    }
}

// ---------------- propagation (round-6 verbatim: fp8 in/out, f32 accum) ----------------

__device__ __forceinline__ void acc8f8(uint2 u, float v, float* acc) {
    f32x2 p0 = __builtin_amdgcn_cvt_pk_f32_fp8((int)u.x, false);
    f32x2 p1 = __builtin_amdgcn_cvt_pk_f32_fp8((int)u.x, true);
    f32x2 p2 = __builtin_amdgcn_cvt_pk_f32_fp8((int)u.y, false);
    f32x2 p3 = __builtin_amdgcn_cvt_pk_f32_fp8((int)u.y, true);
    acc[0] = fmaf(v, p0[0], acc[0]); acc[1] = fmaf(v, p0[1], acc[1]);
    acc[2] = fmaf(v, p1[0], acc[2]); acc[3] = fmaf(v, p1[1], acc[3]);
    acc[4] = fmaf(v, p2[0], acc[4]); acc[5] = fmaf(v, p2[1], acc[5]);
    acc[6] = fmaf(v, p3[0], acc[6]); acc[7] = fmaf(v, p3[1], acc[7]);
}

__global__ __launch_bounds__(256) void prop_kernel(const unsigned char* __restrict__ xin8,
                                                   unsigned char* __restrict__ out8,
                                                   const int* __restrict__ row_ptr,
                                                   const unsigned* __restrict__ cvp, int n) {
    int wid = (blockIdx.x * 256 + threadIdx.x) >> 6;  // one wave per node
    int lane = threadIdx.x & 63;
    if (wid >= n) return;
    int s = row_ptr[wid];
    int deg = row_ptr[wid + 1] - s;
    int g = lane >> 4;        // edge slot group 0..3
    int li = lane & 15;       // 16 lanes cover 128 dims (8 fp8 bytes each)
    float acc[8] = {0.f, 0.f, 0.f, 0.f, 0.f, 0.f, 0.f, 0.f};
    for (int base = 0; base < deg; base += 64) {
        int cnt = deg - base; if (cnt > 64) cnt = 64;
        unsigned el = (lane < cnt) ? cvp[s + base + lane] : 0u;   // coalesced
        for (int q = 0; q < cnt; q += 16) {
            uint2 x[4]; float v[4];
            #pragma unroll
            for (int j = 0; j < 4; ++j) {
                int idx = q + j * 4 + g;
                unsigned c = __shfl(el, idx);
                bool valid = idx < cnt;
                v[j] = valid ? __uint_as_float(c & 0xFFFE0000u) : 0.f;
                x[j] = valid ? *(const uint2*)(xin8 + (size_t)(c & 0x1FFFFu) * DD + li * 8)
                             : make_uint2(0u, 0u);
            }
            #pragma unroll
            for (int j = 0; j < 4; ++j) acc8f8(x[j], v[j], acc);
        }
    }
    #pragma unroll
    for (int k = 0; k < 8; ++k) {
        acc[k] += __shfl_xor(acc[k], 16);
        acc[k] += __shfl_xor(acc[k], 32);
    }
    if (g == 0) {
        uint2 q;
        q.x = pk8(acc[0], acc[1], acc[2], acc[3]);
        q.y = pk8(acc[4], acc[5], acc[6], acc[7]);
        *(uint2*)(out8 + (size_t)wid * DD + li * 8) = q;
    }
}

// ---------------- MFMA matmul: acc = sum_m A_m @ W_m, fused epilogue ----------------
// 16 rows/wave, 64 rows/block (round-6 shape).
// TANH: v = bf2f(base16) + scale*ftanh(acc+bias); outf?=v, out16?=v(bf16), out8=fp8(v)
// RO (requires TANH): additionally y = v_tile @ Wro + rob, via per-wave LDS
//   fragment transpose (each wave owns its 16x128 tile; no cross-wave sync).

template <int NMAT, bool TANH, bool A8, bool RO>
__global__ __launch_bounds__(256) void mfma_mm_kernel(const void* __restrict__ A0,
                                                      const void* __restrict__ A1,
                                                      const void* __restrict__ A2,
                                                      const bfu* __restrict__ Wf,
                                                      const float* __restrict__ bias,
                                                      const bfu* __restrict__ base16,
                                                      float* __restrict__ outf,
                                                      bfu* __restrict__ out16,
                                                      unsigned char* __restrict__ out8,
                                                      const bfu* __restrict__ Wro,
                                                      const float* __restrict__ rob,
                                                      float* __restrict__ yout,
                                                      float scale) {
    int tid = threadIdx.x;
    int wave = tid >> 6, lane = tid & 63;
    int r0 = blockIdx.x * 64 + wave * 16;
    int li = lane & 15, kg = lane >> 4;
    int rowA = r0 + li;
    bool rv = rowA < NN;
    size_t arow = (size_t)(rv ? rowA : 0) * DD;   // elements

    const void* As[3] = {A0, A1, A2};
    short8 a[NMAT][4];
    #pragma unroll
    for (int m = 0; m < NMAT; ++m) {
        #pragma unroll
        for (int ks = 0; ks < 4; ++ks) {
            short8 t;
            if (A8) {
                uint2 u = *(const uint2*)((const unsigned char*)As[m] + arow + ks * 32 + kg * 8);
                t = e8bf(u);
            } else {
                t = *(const short8*)((const bfu*)As[m] + arow + ks * 32 + kg * 8);
            }
            if (!rv) t = (short8)0;
            a[m][ks] = t;
        }
    }

    const short8* Bp = (const short8*)Wf;   // [NMAT][32][64] short8
    f32x4 acc[8];
    #pragma unroll
    for (int nt = 0; nt < 8; ++nt) acc[nt] = (f32x4)(0.f);
    #pragma unroll
    for (int nt = 0; nt < 8; ++nt) {
        #pragma unroll
        for (int m = 0; m < NMAT; ++m) {
            #pragma unroll
            for (int ks = 0; ks < 4; ++ks) {
                short8 b = Bp[m * 2048 + (nt * 4 + ks) * 64 + lane];
                acc[nt] = __builtin_amdgcn_mfma_f32_16x16x32_bf16(a[m][ks], b, acc[nt], 0, 0, 0);
            }
        }
    }

    // per-wave A-fragment-ordered tile of the epilogue result (RO only)
    __shared__ bfu lds_a[RO ? 4 : 1][RO ? 2048 : 1];
    bfu* myt = &lds_a[RO ? wave : 0][0];

    #pragma unroll
    for (int nt = 0; nt < 8; ++nt) {
        int cc = nt * 16 + li;
        float bv = bias[cc];
        #pragma unroll
        for (int rg = 0; rg < 4; ++rg) {
            int rr = r0 + kg * 4 + rg;
            bool v = rr < NN;
            size_t off = (size_t)(v ? rr : 0) * DD + cc;
            float o = acc[nt][rg];
            if (TANH) {
                float ov = v ? (bf2f(base16[off]) + scale * ftanh(o + bv)) : 0.f;
                if (v) {
                    if (outf) outf[off] = ov;
                    if (out16) out16[off] = f2bf(ov);
                    out8[off] = enc8(ov);
                }
                if (RO) {
                    // element (row = kg*4+rg, k = cc) -> A-fragment order
                    int ks = nt >> 1;
                    int kgk = ((nt & 1) << 1) | (li >> 3);
                    int j = li & 7;
                    int row = kg * 4 + rg;
                    myt[(ks * 64 + kgk * 16 + row) * 8 + j] = f2bf(ov);
                }
            } else {
                if (v) outf[off] = o + bv;
            }
        }
    }

    if (RO) {
        // same-wave LDS round-trip: linear per-lane b128 reads, conflict-free
        short8 ar[4];
        #pragma unroll
        for (int ks = 0; ks < 4; ++ks)
            ar[ks] = *(const short8*)&myt[(ks * 64 + lane) * 8];
        const short8* Bro = (const short8*)Wro;
        #pragma unroll
        for (int nt = 0; nt < 8; ++nt) {
            f32x4 ay = (f32x4)(0.f);
            #pragma unroll
            for (int ks = 0; ks < 4; ++ks)
                ay = __builtin_amdgcn_mfma_f32_16x16x32_bf16(ar[ks], Bro[(nt * 4 + ks) * 64 + lane], ay, 0, 0, 0);
            int cc = nt * 16 + li;
            float bv = rob[cc];
            #pragma unroll
            for (int rg = 0; rg < 4; ++rg) {
                int rr = r0 + kg * 4 + rg;
                if (rr < NN) yout[(size_t)rr * DD + cc] = ay[rg] + bv;
            }
        }
    }
}

// ---------------- f32 matmul for embedding: h = x@W + b -> bf16 + fp8 ----------------

__global__ __launch_bounds__(256) void matmul_f32_kernel(const float* __restrict__ A,
                                                         const float* __restrict__ W,
                                                         const float* __restrict__ bias,
                                                         bfu* __restrict__ out16,
                                                         unsigned char* __restrict__ out8) {
    __shared__ float Wl[128][128];
    __shared__ float Al[32][128];
    int tid = threadIdx.x;

    const float4* Wv = (const float4*)W;
    float4* Wlv = (float4*)&Wl[0][0];
    #pragma unroll
    for (int i = 0; i < 16; ++i) Wlv[tid + i * 256] = Wv[tid + i * 256];

    size_t row0 = (size_t)blockIdx.x * 32;
    const float4* Av = (const float4*)(A + row0 * DD);
    float4* Alv = (float4*)&Al[0][0];
    #pragma unroll
    for (int i = 0; i < 4; ++i) Alv[tid + i * 256] = Av[tid + i * 256];
    __syncthreads();

    int cq = tid & 31;
    int rg = tid >> 5;
    float acc[4][4] = {};
    #pragma unroll 8
    for (int k = 0; k < 128; ++k) {
        float4 w = *(const float4*)&Wl[k][cq * 4];
        #pragma unroll
        for (int i = 0; i < 4; ++i) {
            float a = Al[rg * 4 + i][k];
            acc[i][0] = fmaf(a, w.x, acc[i][0]);
            acc[i][1] = fmaf(a, w.y, acc[i][1]);
            acc[i][2] = fmaf(a, w.z, acc[i][2]);
            acc[i][3] = fmaf(a, w.w, acc[i][3]);
        }
    }

    #pragma unroll
    for (int i = 0; i < 4; ++i) {
        size_t r = row0 + rg * 4 + i;
        float4 b = *(const float4*)(bias + cq * 4);
        float4 o = make_float4(acc[i][0] + b.x, acc[i][1] + b.y,
                               acc[i][2] + b.z, acc[i][3] + b.w);
        bfu q0 = f2bf(o.x), q1 = f2bf(o.y), q2 = f2bf(o.z), q3 = f2bf(o.w);
        *(uint2*)(out16 + r * DD + cq * 4) =
            make_uint2((unsigned)q0 | ((unsigned)q1 << 16), (unsigned)q2 | ((unsigned)q3 << 16));
        *(unsigned*)(out8 + r * DD + cq * 4) = pk8(o.x, o.y, o.z, o.w);
    }
}

// ---------------- launch ----------------

extern "C" void kernel_launch(void* const* d_in, const int* in_sizes, int n_in,
                              void* d_out, int out_size, void* d_ws, size_t ws_size,
                              hipStream_t stream) {
    const float* x      = (const float*)d_in[0];
    const int*   eidx   = (const int*)d_in[1];
    const float* emb_w  = (const float*)d_in[3];
    const float* emb_b  = (const float*)d_in[4];
    const float* conv_ws = (const float*)d_in[5];
    const float* conv_b = (const float*)d_in[6];
    const float* ro_w   = (const float*)d_in[7];
    const float* ro_b   = (const float*)d_in[8];

    const int* src = eidx;
    const int* dst = eidx + EE;

    float* y  = (float*)d_out;                   // [N,128] final output
    float* hm = y + (size_t)NN * DD;             // [N,128] h_middle f32 output

    char* p = (char*)d_ws;
    const size_t FB2 = (size_t)NN * DD * sizeof(bfu);   // 25.6 MB
    const size_t FB1 = (size_t)NN * DD;                 // 12.8 MB
    bfu* h16     = (bfu*)p;                 p += FB2;   // bf16 master state
    unsigned char* h8  = (unsigned char*)p; p += FB1;
    unsigned char* hm8 = (unsigned char*)p; p += FB1;
    unsigned char* bufA8 = (unsigned char*)p; p += FB1;
    unsigned char* bufB8 = (unsigned char*)p; p += FB1;
    float* dinv  = (float*)p;               p += (size_t)NN * 4;
    int* ideg    = (int*)p;                 p += (size_t)NN * 4;
    int* row_ptr = (int*)p;                 p += (size_t)(NN + 1) * 4;
    int* cursor  = (int*)p;                 p += (size_t)NN * 4;
    int* partials = (int*)p;                p += (size_t)512 * 4;
    bfu* Wf      = (bfu*)p;                 p += (size_t)4 * 16384 * sizeof(bfu);
    unsigned* cvp = (unsigned*)p;           p += (size_t)EE * 4;

    const int NB = (NN + 255) / 256;   // 391

    hipMemsetAsync(ideg, 0, (size_t)NN * 4, stream);
    count_deg_kernel<<<EE / 256, 256, 0, stream>>>(dst, ideg, EE);
    dinv_kernel<<<NB, 256, 0, stream>>>(ideg, dinv, NN);
    partial_sum_kernel<<<NB, 256, 0, stream>>>(ideg, partials, NN);
    scan_partials_kernel<<<1, 512, 0, stream>>>(partials, row_ptr, NB, NN);
    scan_block_kernel<<<NB, 256, 0, stream>>>(ideg, partials, row_ptr, cursor, NN);
    fill_csr_kernel<<<EE / 256, 256, 0, stream>>>(src, dst, dinv, cursor, cvp, EE);
    wfrag_kernel<<<4, 256, 0, stream>>>(conv_ws, ro_w, Wf);

    const int MM_GRID   = (NN + 63) / 64;     // 1563
    const int PROP_GRID = NN * 64 / 256;      // 25000

    // h = x @ emb_w + emb_b  (bf16 master + fp8 shadow)
    matmul_f32_kernel<<<NN / 32, 256, 0, stream>>>(x, emb_w, emb_b, h16, h8);

    for (int t = 0; t < 4; ++t) {
        // hm = h + 0.05*tanh(h@W0 + (Ph)@W1 + (P2h)@W2 + b)
        prop_kernel<<<PROP_GRID, 256, 0, stream>>>(h8, bufA8, row_ptr, cvp, NN);
        prop_kernel<<<PROP_GRID, 256, 0, stream>>>(bufA8, bufB8, row_ptr, cvp, NN);
        if (t < 3) {
            mfma_mm_kernel<3, true, true, false><<<MM_GRID, 256, 0, stream>>>(
                h8, bufA8, bufB8, Wf, conv_b, h16,
                nullptr, nullptr, hm8, nullptr, nullptr, nullptr, 0.5f * EPSc);

            // h = h + 0.1*tanh(hm@W0 + (Phm)@W1 + (P2hm)@W2 + b)
            prop_kernel<<<PROP_GRID, 256, 0, stream>>>(hm8, bufA8, row_ptr, cvp, NN);
            prop_kernel<<<PROP_GRID, 256, 0, stream>>>(bufA8, bufB8, row_ptr, cvp, NN);
            mfma_mm_kernel<3, true, true, false><<<MM_GRID, 256, 0, stream>>>(
                hm8, bufA8, bufB8, Wf, conv_b, h16,
                nullptr, h16, h8, nullptr, nullptr, nullptr, EPSc);
        } else {
            // final midpoint: write hm (f32 output) + hm8, and fuse y = hm @ ro_w + ro_b.
            // The trailing h-update of the reference is dead code (h never read again).
            mfma_mm_kernel<3, true, true, true><<<MM_GRID, 256, 0, stream>>>(
                h8, bufA8, bufB8, Wf, conv_b, h16,
                hm, nullptr, hm8, Wf + 3 * 16384, ro_b, y, 0.5f * EPSc);
        }
    }
}

// Round 11
// 1089.565 us; speedup vs baseline: 1.8600x; 1.0472x over previous
//
#include <hip/hip_runtime.h>
#include <hip/hip_bf16.h>

#define NN 100000
#define EE 1600000
#define DD 128
#define EPSc 0.1f
#define NBK 256        // dst-range buckets
#define BKDIV 391      // dsts per bucket (391*256 >= NN)
#define BKCAP 7168     // max edges per bucket (avg 6250, >10 sigma pad)

typedef unsigned short bfu;
typedef __attribute__((ext_vector_type(8))) short short8;   // 8 bf16 = 4 VGPRs
typedef __attribute__((ext_vector_type(4))) float f32x4;
typedef __attribute__((ext_vector_type(2))) float f32x2;

__device__ __forceinline__ float bf2f(bfu s) {
    union { unsigned u; float f; } c; c.u = ((unsigned)s) << 16; return c.f;
}
__device__ __forceinline__ bfu f2bf(float f) {
    union { float f; unsigned u; } c; c.f = f;
    unsigned u = c.u + 0x7fffu + ((c.u >> 16) & 1u);   // RNE
    return (bfu)(u >> 16);
}
__device__ __forceinline__ unsigned pk8(float a, float b, float c, float d) {
    int r = 0;
    r = __builtin_amdgcn_cvt_pk_fp8_f32(a, b, r, false);
    r = __builtin_amdgcn_cvt_pk_fp8_f32(c, d, r, true);
    return (unsigned)r;
}
__device__ __forceinline__ unsigned char enc8(float a) {
    return (unsigned char)(__builtin_amdgcn_cvt_pk_fp8_f32(a, a, 0, false) & 0xFF);
}
__device__ __forceinline__ short8 e8bf(uint2 u) {
    f32x2 p0 = __builtin_amdgcn_cvt_pk_f32_fp8((int)u.x, false);
    f32x2 p1 = __builtin_amdgcn_cvt_pk_f32_fp8((int)u.x, true);
    f32x2 p2 = __builtin_amdgcn_cvt_pk_f32_fp8((int)u.y, false);
    f32x2 p3 = __builtin_amdgcn_cvt_pk_f32_fp8((int)u.y, true);
    short8 s;
    s[0] = (short)f2bf(p0[0]); s[1] = (short)f2bf(p0[1]);
    s[2] = (short)f2bf(p1[0]); s[3] = (short)f2bf(p1[1]);
    s[4] = (short)f2bf(p2[0]); s[5] = (short)f2bf(p2[1]);
    s[6] = (short)f2bf(p3[0]); s[7] = (short)f2bf(p3[1]);
    return s;
}
// fast tanh: (e^{2x}-1)/(e^{2x}+1), clamped so exp can't overflow
__device__ __forceinline__ float ftanh(float x) {
    float xc = fminf(fmaxf(x, -9.0f), 9.0f);
    float e = __expf(2.0f * xc);
    return (e - 1.0f) * __builtin_amdgcn_rcpf(e + 1.0f);
}

// ---------------- CSR build ----------------

__global__ __launch_bounds__(256) void count_deg_kernel(const int* __restrict__ dst,
                                                        int* __restrict__ ideg, int e_cnt) {
    int e = blockIdx.x * 256 + threadIdx.x;
    if (e < e_cnt) atomicAdd(&ideg[dst[e]], 1);
}

__global__ __launch_bounds__(256) void dinv_kernel(const int* __restrict__ ideg,
                                                   float* __restrict__ dinv, int n) {
    int i = blockIdx.x * 256 + threadIdx.x;
    if (i < n) {
        int d = ideg[i];
        dinv[i] = (d > 0) ? rsqrtf((float)d) : 0.0f;
    }
}

__global__ __launch_bounds__(256) void partial_sum_kernel(const int* __restrict__ ideg,
                                                          int* __restrict__ partials, int n) {
    __shared__ int sm[256];
    int i = blockIdx.x * 256 + threadIdx.x;
    sm[threadIdx.x] = (i < n) ? ideg[i] : 0;
    __syncthreads();
    for (int off = 128; off > 0; off >>= 1) {
        if ((int)threadIdx.x < off) sm[threadIdx.x] += sm[threadIdx.x + off];
        __syncthreads();
    }
    if (threadIdx.x == 0) partials[blockIdx.x] = sm[0];
}

__global__ __launch_bounds__(512) void scan_partials_kernel(int* __restrict__ partials,
                                                            int* __restrict__ row_ptr,
                                                            int nb, int n) {
    __shared__ int sm[512];
    int v = ((int)threadIdx.x < nb) ? partials[threadIdx.x] : 0;
    sm[threadIdx.x] = v;
    __syncthreads();
    for (int off = 1; off < 512; off <<= 1) {
        int t = (threadIdx.x >= (unsigned)off) ? sm[threadIdx.x - off] : 0;
        __syncthreads();
        sm[threadIdx.x] += t;
        __syncthreads();
    }
    if ((int)threadIdx.x < nb) partials[threadIdx.x] = sm[threadIdx.x] - v;
    if (threadIdx.x == 511) row_ptr[n] = sm[511];
}

__global__ __launch_bounds__(256) void scan_block_kernel(const int* __restrict__ ideg,
                                                         const int* __restrict__ partials,
                                                         int* __restrict__ row_ptr, int n) {
    __shared__ int sm[256];
    int i = blockIdx.x * 256 + threadIdx.x;
    int v = (i < n) ? ideg[i] : 0;
    sm[threadIdx.x] = v;
    __syncthreads();
    for (int off = 1; off < 256; off <<= 1) {
        int t = (threadIdx.x >= (unsigned)off) ? sm[threadIdx.x - off] : 0;
        __syncthreads();
        sm[threadIdx.x] += t;
        __syncthreads();
    }
    if (i < n) row_ptr[i] = partials[blockIdx.x] + sm[threadIdx.x] - v;
}

// pass 1: bin edges into 256 dst-range buckets. Block-local LDS histogram ->
// ONE global cursor update per (block,bucket) -> no same-address atomic storm;
// segment writes are 128B-run coalesced.
__global__ __launch_bounds__(256) void bin_kernel(const int* __restrict__ src,
                                                  const int* __restrict__ dst,
                                                  int* __restrict__ bcur,
                                                  uint2* __restrict__ store, int e_cnt) {
    __shared__ int lcnt[NBK];
    __shared__ int lbase[NBK];
    int e0 = blockIdx.x * 4096;
    lcnt[threadIdx.x] = 0;
    __syncthreads();
    for (int k = 0; k < 16; ++k) {
        int e = e0 + k * 256 + (int)threadIdx.x;
        if (e < e_cnt) atomicAdd(&lcnt[(unsigned)dst[e] / BKDIV], 1);
    }
    __syncthreads();
    int c = lcnt[threadIdx.x];
    lbase[threadIdx.x] = (c > 0) ? atomicAdd(&bcur[threadIdx.x], c) : 0;
    __syncthreads();
    lcnt[threadIdx.x] = 0;
    __syncthreads();
    for (int k = 0; k < 16; ++k) {
        int e = e0 + k * 256 + (int)threadIdx.x;
        if (e < e_cnt) {
            int d = dst[e];
            unsigned b = (unsigned)d / BKDIV;
            int p = atomicAdd(&lcnt[b], 1);
            int idx = lbase[b] + p;
            if (idx < BKCAP)
                store[(size_t)b * BKCAP + idx] = make_uint2((unsigned)src[e], (unsigned)d);
        }
    }
}

// pass 2: one block per bucket; scatter into an L2-local 25KB cvp window via
// LDS per-dst cursors. packed edge: top 15 bits = f32 val bits[31:17], low 17 = col.
__global__ __launch_bounds__(256) void place_kernel(const uint2* __restrict__ store,
                                                    const int* __restrict__ bcur,
                                                    const int* __restrict__ row_ptr,
                                                    const float* __restrict__ dinv,
                                                    unsigned* __restrict__ cvp) {
    __shared__ int cur[BKDIV];
    int g = blockIdx.x;
    int d0 = g * BKDIV;
    for (int i = threadIdx.x; i < BKDIV; i += 256) {
        int d = d0 + i;
        cur[i] = (d < NN) ? row_ptr[d] : 0;
    }
    __syncthreads();
    int cnt = bcur[g];
    if (cnt > BKCAP) cnt = BKCAP;
    for (int i = threadIdx.x; i < cnt; i += 256) {
        uint2 w = store[(size_t)g * BKCAP + i];
        int s = (int)w.x, d = (int)w.y;
        int pos = atomicAdd(&cur[d - d0], 1);
        unsigned vb = __float_as_uint(dinv[s] * dinv[d]);
        unsigned r = vb + 0xFFFFu + ((vb >> 17) & 1u);   // RNE to 15-bit float
        cvp[pos] = (r & 0xFFFE0000u) | (unsigned)s;
    }
}

// ------------- weight -> bf16 MFMA-fragment-order transform (5 matrices) -------------

__global__ __launch_bounds__(256) void wfrag_kernel(const float* __restrict__ conv_ws,
                                                    const float* __restrict__ ro_w,
                                                    const float* __restrict__ emb_w,
                                                    bfu* __restrict__ Wf) {
    int m = blockIdx.x;   // 0..4
    const float* W = (m < 3) ? conv_ws + m * 16384 : (m == 3 ? ro_w : emb_w);
    bfu* T = Wf + m * 16384;
    for (int j = 0; j < 64; ++j) {
        int i = threadIdx.x + j * 256;       // i = k*128 + n
        int k = i >> 7, n = i & 127;
        int nt = n >> 4, ks = k >> 5, kg = (k >> 3) & 3, jj = k & 7;
        int l = kg * 16 + (n & 15);
        int flat = ((nt * 4 + ks) * 64 + l) * 8 + jj;
        T[flat] = f2bf(W[i]);
    }
}

// ---------------- propagation (fp8 in / fp8 out, f32 accum) ----------------

__device__ __forceinline__ void acc8f8(uint2 u, float v, float* acc) {
    f32x2 p0 = __builtin_amdgcn_cvt_pk_f32_fp8((int)u.x, false);
    f32x2 p1 = __builtin_amdgcn_cvt_pk_f32_fp8((int)u.x, true);
    f32x2 p2 = __builtin_amdgcn_cvt_pk_f32_fp8((int)u.y, false);
    f32x2 p3 = __builtin_amdgcn_cvt_pk_f32_fp8((int)u.y, true);
    acc[0] = fmaf(v, p0[0], acc[0]); acc[1] = fmaf(v, p0[1], acc[1]);
    acc[2] = fmaf(v, p1[0], acc[2]); acc[3] = fmaf(v, p1[1], acc[3]);
    acc[4] = fmaf(v, p2[0], acc[4]); acc[5] = fmaf(v, p2[1], acc[5]);
    acc[6] = fmaf(v, p3[0], acc[6]); acc[7] = fmaf(v, p3[1], acc[7]);
}

__global__ __launch_bounds__(256) void prop_kernel(const unsigned char* __restrict__ xin8,
                                                   unsigned char* __restrict__ out8,
                                                   const int* __restrict__ row_ptr,
                                                   const unsigned* __restrict__ cvp, int n) {
    int wid = (blockIdx.x * 256 + threadIdx.x) >> 6;  // one wave per node
    int lane = threadIdx.x & 63;
    if (wid >= n) return;
    int s = row_ptr[wid];
    int deg = row_ptr[wid + 1] - s;
    int g = lane >> 4;        // edge slot group 0..3
    int li = lane & 15;       // 16 lanes cover 128 dims (8 fp8 bytes each)
    float acc[8] = {0.f, 0.f, 0.f, 0.f, 0.f, 0.f, 0.f, 0.f};
    for (int base = 0; base < deg; base += 64) {
        int cnt = deg - base; if (cnt > 64) cnt = 64;
        unsigned el = (lane < cnt) ? cvp[s + base + lane] : 0u;   // coalesced
        for (int q = 0; q < cnt; q += 16) {
            uint2 x[4]; float v[4];
            #pragma unroll
            for (int j = 0; j < 4; ++j) {
                int idx = q + j * 4 + g;
                unsigned c = __shfl(el, idx);
                bool valid = idx < cnt;
                v[j] = valid ? __uint_as_float(c & 0xFFFE0000u) : 0.f;
                x[j] = valid ? *(const uint2*)(xin8 + (size_t)(c & 0x1FFFFu) * DD + li * 8)
                             : make_uint2(0u, 0u);
            }
            #pragma unroll
            for (int j = 0; j < 4; ++j) acc8f8(x[j], v[j], acc);
        }
    }
    #pragma unroll
    for (int k = 0; k < 8; ++k) {
        acc[k] += __shfl_xor(acc[k], 16);
        acc[k] += __shfl_xor(acc[k], 32);
    }
    if (g == 0) {
        uint2 q;
        q.x = pk8(acc[0], acc[1], acc[2], acc[3]);
        q.y = pk8(acc[4], acc[5], acc[6], acc[7]);
        *(uint2*)(out8 + (size_t)wid * DD + li * 8) = q;
    }
}

// ---------------- MFMA matmul: acc = sum_m A_m @ W_m, fused epilogue ----------------
// 16 rows/wave, 64 rows/block.
// TANH: v = bf2f(base16) + scale*ftanh(acc+bias); outf?=v, out16?=v(bf16), out8=fp8(v)
// RO (requires TANH): additionally y = v_tile @ Wro + rob via per-wave LDS transpose.

template <int NMAT, bool TANH, bool A8, bool RO>
__global__ __launch_bounds__(256) void mfma_mm_kernel(const void* __restrict__ A0,
                                                      const void* __restrict__ A1,
                                                      const void* __restrict__ A2,
                                                      const bfu* __restrict__ Wf,
                                                      const float* __restrict__ bias,
                                                      const bfu* __restrict__ base16,
                                                      float* __restrict__ outf,
                                                      bfu* __restrict__ out16,
                                                      unsigned char* __restrict__ out8,
                                                      const bfu* __restrict__ Wro,
                                                      const float* __restrict__ rob,
                                                      float* __restrict__ yout,
                                                      float scale) {
    int tid = threadIdx.x;
    int wave = tid >> 6, lane = tid & 63;
    int r0 = blockIdx.x * 64 + wave * 16;
    int li = lane & 15, kg = lane >> 4;
    int rowA = r0 + li;
    bool rv = rowA < NN;
    size_t arow = (size_t)(rv ? rowA : 0) * DD;   // elements

    const void* As[3] = {A0, A1, A2};
    short8 a[NMAT][4];
    #pragma unroll
    for (int m = 0; m < NMAT; ++m) {
        #pragma unroll
        for (int ks = 0; ks < 4; ++ks) {
            short8 t;
            if (A8) {
                uint2 u = *(const uint2*)((const unsigned char*)As[m] + arow + ks * 32 + kg * 8);
                t = e8bf(u);
            } else {
                t = *(const short8*)((const bfu*)As[m] + arow + ks * 32 + kg * 8);
            }
            if (!rv) t = (short8)0;
            a[m][ks] = t;
        }
    }

    const short8* Bp = (const short8*)Wf;   // [NMAT][32][64] short8
    f32x4 acc[8];
    #pragma unroll
    for (int nt = 0; nt < 8; ++nt) acc[nt] = (f32x4)(0.f);
    #pragma unroll
    for (int nt = 0; nt < 8; ++nt) {
        #pragma unroll
        for (int m = 0; m < NMAT; ++m) {
            #pragma unroll
            for (int ks = 0; ks < 4; ++ks) {
                short8 b = Bp[m * 2048 + (nt * 4 + ks) * 64 + lane];
                acc[nt] = __builtin_amdgcn_mfma_f32_16x16x32_bf16(a[m][ks], b, acc[nt], 0, 0, 0);
            }
        }
    }

    __shared__ bfu lds_a[RO ? 4 : 1][RO ? 2048 : 1];
    bfu* myt = &lds_a[RO ? wave : 0][0];

    #pragma unroll
    for (int nt = 0; nt < 8; ++nt) {
        int cc = nt * 16 + li;
        float bv = bias[cc];
        #pragma unroll
        for (int rg = 0; rg < 4; ++rg) {
            int rr = r0 + kg * 4 + rg;
            bool v = rr < NN;
            size_t off = (size_t)(v ? rr : 0) * DD + cc;
            float o = acc[nt][rg];
            if (TANH) {
                float ov = v ? (bf2f(base16[off]) + scale * ftanh(o + bv)) : 0.f;
                if (v) {
                    if (outf) outf[off] = ov;
                    if (out16) out16[off] = f2bf(ov);
                    out8[off] = enc8(ov);
                }
                if (RO) {
                    int ks = nt >> 1;
                    int kgk = ((nt & 1) << 1) | (li >> 3);
                    int j = li & 7;
                    int row = kg * 4 + rg;
                    myt[(ks * 64 + kgk * 16 + row) * 8 + j] = f2bf(ov);
                }
            } else {
                if (v) outf[off] = o + bv;
            }
        }
    }

    if (RO) {
        short8 ar[4];
        #pragma unroll
        for (int ks = 0; ks < 4; ++ks)
            ar[ks] = *(const short8*)&myt[(ks * 64 + lane) * 8];
        const short8* Bro = (const short8*)Wro;
        #pragma unroll
        for (int nt = 0; nt < 8; ++nt) {
            f32x4 ay = (f32x4)(0.f);
            #pragma unroll
            for (int ks = 0; ks < 4; ++ks)
                ay = __builtin_amdgcn_mfma_f32_16x16x32_bf16(ar[ks], Bro[(nt * 4 + ks) * 64 + lane], ay, 0, 0, 0);
            int cc = nt * 16 + li;
            float bv = rob[cc];
            #pragma unroll
            for (int rg = 0; rg < 4; ++rg) {
                int rr = r0 + kg * 4 + rg;
                if (rr < NN) yout[(size_t)rr * DD + cc] = ay[rg] + bv;
            }
        }
    }
}

// ---------------- embedding via MFMA: h = x@emb_w + emb_b -> bf16 + fp8 ----------------

__global__ __launch_bounds__(256) void emb_mfma_kernel(const float* __restrict__ x,
                                                       const bfu* __restrict__ Wfe,
                                                       const float* __restrict__ bias,
                                                       bfu* __restrict__ out16,
                                                       unsigned char* __restrict__ out8) {
    int tid = threadIdx.x;
    int wave = tid >> 6, lane = tid & 63;
    int r0 = blockIdx.x * 64 + wave * 16;
    int li = lane & 15, kg = lane >> 4;
    int rowA = r0 + li;
    bool rv = rowA < NN;
    size_t arow = (size_t)(rv ? rowA : 0) * DD;

    short8 a[4];
    #pragma unroll
    for (int ks = 0; ks < 4; ++ks) {
        const float* px = x + arow + ks * 32 + kg * 8;
        float4 lo = *(const float4*)px;
        float4 hi = *(const float4*)(px + 4);
        short8 t;
        t[0] = (short)f2bf(lo.x); t[1] = (short)f2bf(lo.y);
        t[2] = (short)f2bf(lo.z); t[3] = (short)f2bf(lo.w);
        t[4] = (short)f2bf(hi.x); t[5] = (short)f2bf(hi.y);
        t[6] = (short)f2bf(hi.z); t[7] = (short)f2bf(hi.w);
        if (!rv) t = (short8)0;
        a[ks] = t;
    }

    const short8* Bp = (const short8*)Wfe;
    #pragma unroll
    for (int nt = 0; nt < 8; ++nt) {
        f32x4 acc = (f32x4)(0.f);
        #pragma unroll
        for (int ks = 0; ks < 4; ++ks)
            acc = __builtin_amdgcn_mfma_f32_16x16x32_bf16(a[ks], Bp[(nt * 4 + ks) * 64 + lane], acc, 0, 0, 0);
        int cc = nt * 16 + li;
        float bv = bias[cc];
        #pragma unroll
        for (int rg = 0; rg < 4; ++rg) {
            int rr = r0 + kg * 4 + rg;
            if (rr < NN) {
                size_t off = (size_t)rr * DD + cc;
                float o = acc[rg] + bv;
                out16[off] = f2bf(o);
                out8[off] = enc8(o);
            }
        }
    }
}

// ---------------- launch ----------------

extern "C" void kernel_launch(void* const* d_in, const int* in_sizes, int n_in,
                              void* d_out, int out_size, void* d_ws, size_t ws_size,
                              hipStream_t stream) {
    const float* x      = (const float*)d_in[0];
    const int*   eidx   = (const int*)d_in[1];
    const float* emb_w  = (const float*)d_in[3];
    const float* emb_b  = (const float*)d_in[4];
    const float* conv_ws = (const float*)d_in[5];
    const float* conv_b = (const float*)d_in[6];
    const float* ro_w   = (const float*)d_in[7];
    const float* ro_b   = (const float*)d_in[8];

    const int* src = eidx;
    const int* dst = eidx + EE;

    float* y  = (float*)d_out;                   // [N,128] final output
    float* hm = y + (size_t)NN * DD;             // [N,128] h_middle f32 output

    char* p = (char*)d_ws;
    const size_t FB2 = (size_t)NN * DD * sizeof(bfu);   // 25.6 MB
    const size_t FB1 = (size_t)NN * DD;                 // 12.8 MB
    bfu* h16     = (bfu*)p;                 p += FB2;   // bf16 master state
    unsigned char* h8  = (unsigned char*)p; p += FB1;
    unsigned char* hm8 = (unsigned char*)p; p += FB1;
    unsigned char* bufA8 = (unsigned char*)p; p += FB1;
    unsigned char* bufB8 = (unsigned char*)p; p += FB1;
    float* dinv  = (float*)p;               p += (size_t)NN * 4;
    int* ideg    = (int*)p;                 p += (size_t)NN * 4;
    int* row_ptr = (int*)p;                 p += (size_t)(NN + 1) * 4;
    int* partials = (int*)p;                p += (size_t)512 * 4;
    int* bcur    = (int*)p;                 p += (size_t)NBK * 4;
    uint2* store = (uint2*)p;               p += (size_t)NBK * BKCAP * 8;  // 14.7 MB
    bfu* Wf      = (bfu*)p;                 p += (size_t)5 * 16384 * sizeof(bfu);
    unsigned* cvp = (unsigned*)p;           p += (size_t)EE * 4;

    const int NB = (NN + 255) / 256;   // 391
    const int EB = (EE + 4095) / 4096; // 391

    hipMemsetAsync(ideg, 0, (size_t)NN * 4, stream);
    hipMemsetAsync(bcur, 0, (size_t)NBK * 4, stream);
    count_deg_kernel<<<EE / 256, 256, 0, stream>>>(dst, ideg, EE);
    dinv_kernel<<<NB, 256, 0, stream>>>(ideg, dinv, NN);
    partial_sum_kernel<<<NB, 256, 0, stream>>>(ideg, partials, NN);
    scan_partials_kernel<<<1, 512, 0, stream>>>(partials, row_ptr, NB, NN);
    scan_block_kernel<<<NB, 256, 0, stream>>>(ideg, partials, row_ptr, NN);
    bin_kernel<<<EB, 256, 0, stream>>>(src, dst, bcur, store, EE);
    place_kernel<<<NBK, 256, 0, stream>>>(store, bcur, row_ptr, dinv, cvp);
    wfrag_kernel<<<5, 256, 0, stream>>>(conv_ws, ro_w, emb_w, Wf);

    const int MM_GRID   = (NN + 63) / 64;     // 1563
    const int PROP_GRID = NN * 64 / 256;      // 25000

    // h = x @ emb_w + emb_b  (bf16 master + fp8 shadow)
    emb_mfma_kernel<<<MM_GRID, 256, 0, stream>>>(x, Wf + 4 * 16384, emb_b, h16, h8);

    for (int t = 0; t < 4; ++t) {
        // hm = h + 0.05*tanh(h@W0 + (Ph)@W1 + (P2h)@W2 + b)
        prop_kernel<<<PROP_GRID, 256, 0, stream>>>(h8, bufA8, row_ptr, cvp, NN);
        prop_kernel<<<PROP_GRID, 256, 0, stream>>>(bufA8, bufB8, row_ptr, cvp, NN);
        if (t < 3) {
            mfma_mm_kernel<3, true, true, false><<<MM_GRID, 256, 0, stream>>>(
                h8, bufA8, bufB8, Wf, conv_b, h16,
                nullptr, nullptr, hm8, nullptr, nullptr, nullptr, 0.5f * EPSc);

            // h = h + 0.1*tanh(hm@W0 + (Phm)@W1 + (P2hm)@W2 + b)
            prop_kernel<<<PROP_GRID, 256, 0, stream>>>(hm8, bufA8, row_ptr, cvp, NN);
            prop_kernel<<<PROP_GRID, 256, 0, stream>>>(bufA8, bufB8, row_ptr, cvp, NN);
            mfma_mm_kernel<3, true, true, false><<<MM_GRID, 256, 0, stream>>>(
                hm8, bufA8, bufB8, Wf, conv_b, h16,
                nullptr, h16, h8, nullptr, nullptr, nullptr, EPSc);
        } else {
            // final midpoint: write hm (f32 output) + hm8, fuse y = hm @ ro_w + ro_b.
            // The trailing h-update of the reference is dead code (h never read again).
            mfma_mm_kernel<3, true, true, true><<<MM_GRID, 256, 0, stream>>>(
                h8, bufA8, bufB8, Wf, conv_b, h16,
                hm, nullptr, hm8, Wf + 3 * 16384, ro_b, y, 0.5f * EPSc);
        }
    }
}